// Round 9
// baseline (776.253 us; speedup 1.0000x reference)
//
#include <hip/hip_runtime.h>

#define N_NODES 100000
#define E_EDGES 3200000
#define F_IN    1433
#define K_PAD   1440   // w1t padded K (9*160)
#define NCH     98     // scan chunks of 1024
#define KPH     160    // k per LDS phase (9 phases)
#define PSTR    164    // LDS stride in halves (328B: 8B-aligned b64, odd-ish dword stride)

typedef _Float16 f16x4 __attribute__((ext_vector_type(4)));
typedef _Float16 f16x8 __attribute__((ext_vector_type(8)));
typedef float    f32x4 __attribute__((ext_vector_type(4)));

// ---------------- init: counts=0 + W1^T fp16 [64][K_PAD] zero-padded ----------------
__global__ void k_init(const float* __restrict__ w1, _Float16* __restrict__ w1t,
                       int* __restrict__ counts) {
    int i = blockIdx.x * 256 + threadIdx.x;
    if (i < N_NODES) counts[i] = 0;
    if (i < 64 * K_PAD) {
        int n = i / K_PAD, k = i - n * K_PAD;
        float v = (k < F_IN) ? w1[(size_t)k * 64 + n] : 0.f;
        w1t[i] = (_Float16)v;
    }
}

__global__ void k_hist(const int* __restrict__ dst, int* __restrict__ counts) {
    int idx = blockIdx.x * 256 + threadIdx.x;      // 3125*256*4 = 3.2M
    int4 d4 = ((const int4*)dst)[idx];
    atomicAdd(&counts[d4.x], 1);
    atomicAdd(&counts[d4.y], 1);
    atomicAdd(&counts[d4.z], 1);
    atomicAdd(&counts[d4.w], 1);
}

// ---------------- exclusive scan of counts (chunked) ----------------
__global__ void k_scan_a(const int* __restrict__ counts, int* __restrict__ csum) {
    __shared__ int sh[256];
    int b = blockIdx.x, t = threadIdx.x;
    int s = 0;
    for (int j = 0; j < 4; ++j) {
        int idx = b * 1024 + j * 256 + t;
        if (idx < N_NODES) s += counts[idx];
    }
    sh[t] = s; __syncthreads();
    for (int off = 128; off > 0; off >>= 1) {
        if (t < off) sh[t] += sh[t + off];
        __syncthreads();
    }
    if (t == 0) csum[b] = sh[0];
}

__global__ void k_scan_b(int* __restrict__ csum) {
    __shared__ int sh[128];
    int t = threadIdx.x;
    int v = (t < NCH) ? csum[t] : 0;
    sh[t] = v; __syncthreads();
    for (int off = 1; off < 128; off <<= 1) {
        int u = (t >= off) ? sh[t - off] : 0;
        __syncthreads();
        sh[t] += u;
        __syncthreads();
    }
    if (t < NCH) csum[t] = sh[t] - v;   // exclusive
}

__global__ void k_scan_c(const int* __restrict__ counts, const int* __restrict__ csum,
                         int* __restrict__ offsets, int* __restrict__ cursor) {
    __shared__ int sh[256];
    int b = blockIdx.x, t = threadIdx.x;
    int base = b * 1024 + t * 4;
    int c0 = (base + 0 < N_NODES) ? counts[base + 0] : 0;
    int c1 = (base + 1 < N_NODES) ? counts[base + 1] : 0;
    int c2 = (base + 2 < N_NODES) ? counts[base + 2] : 0;
    int c3 = (base + 3 < N_NODES) ? counts[base + 3] : 0;
    int tot = c0 + c1 + c2 + c3;
    sh[t] = tot; __syncthreads();
    for (int off = 1; off < 256; off <<= 1) {
        int v = (t >= off) ? sh[t - off] : 0;
        __syncthreads();
        sh[t] += v;
        __syncthreads();
    }
    int excl = sh[t] - tot;
    int o = csum[b] + excl;
    if (base + 0 < N_NODES) { offsets[base + 0] = o;            cursor[base + 0] = o; }
    if (base + 1 < N_NODES) { int q = o + c0;      offsets[base + 1] = q; cursor[base + 1] = q; }
    if (base + 2 < N_NODES) { int q = o + c0 + c1; offsets[base + 2] = q; cursor[base + 2] = q; }
    if (base + 3 < N_NODES) { int q = o + c0 + c1 + c2; offsets[base + 3] = q; cursor[base + 3] = q; }
}

__global__ void k_scatter(const int* __restrict__ src, const int* __restrict__ dst,
                          int* __restrict__ cursor, int* __restrict__ sorted_src) {
    int idx = blockIdx.x * 256 + threadIdx.x;
    int4 s4 = ((const int4*)src)[idx];
    int4 d4 = ((const int4*)dst)[idx];
    int p;
    p = atomicAdd(&cursor[d4.x], 1); sorted_src[p] = s4.x;
    p = atomicAdd(&cursor[d4.y], 1); sorted_src[p] = s4.y;
    p = atomicAdd(&cursor[d4.z], 1); sorted_src[p] = s4.z;
    p = atomicAdd(&cursor[d4.w], 1); sorted_src[p] = s4.w;
}

// ---------------- GEMM1 + fused att1: h1 = x @ W1, a_s1/a_d1 ----------------
// Both A and B in LDS; ALL global loads contiguous (no 16-row-stride fragment
// loads). 64-row blocks, 9 K-phases of 160; wave w = rows w*16, all 64 cols.
__global__ __launch_bounds__(256) void k_gemm1(const float* __restrict__ x,
                                               const _Float16* __restrict__ w1t,
                                               const float* __restrict__ att_src1,
                                               const float* __restrict__ att_dst1,
                                               _Float16* __restrict__ h1,
                                               float* __restrict__ a_s1,
                                               float* __restrict__ a_d1) {
    __shared__ __align__(16) _Float16 As[64 * PSTR];   // 20992 B
    __shared__ __align__(16) _Float16 Bs[64 * PSTR];   // 20992 B  -> 3 blocks/CU
    const int tid  = threadIdx.x;
    const int lane = tid & 63;
    const int wave = tid >> 6;
    const int l16  = lane & 15;
    const int l4   = lane >> 4;
    const int brow0 = blockIdx.x * 64;

    f32x4 acc[4] = {};
    for (int ph = 0; ph < 9; ++ph) {
        const int k0 = ph * KPH;
        __syncthreads();                 // prev phase's LDS reads done
        // ---- stage A: 64 rows x 160 fp32 -> fp16 (per-row contiguous float4) ----
        #pragma unroll
        for (int it = 0; it < 10; ++it) {
            int i   = it * 256 + tid;    // 0..2559
            int row = i / 40, q = i - row * 40;
            int grow = brow0 + row;
            if (grow > N_NODES - 1) grow = N_NODES - 1;
            const float* gp = x + (size_t)grow * F_IN + k0 + q * 4;
            f16x4 hv;
            if (ph < 8) {
                float4 v = *(const float4*)gp;
                hv = { (_Float16)v.x, (_Float16)v.y, (_Float16)v.z, (_Float16)v.w };
            } else {
                int kb = k0 + q * 4;
                #pragma unroll
                for (int j = 0; j < 4; ++j)
                    hv[j] = (kb + j < F_IN) ? (_Float16)gp[j] : (_Float16)0.f;
            }
            *(f16x4*)(&As[row * PSTR + q * 4]) = hv;
        }
        // ---- stage B: 64 cols x 160 fp16 (from L2-resident w1t) ----
        #pragma unroll
        for (int it = 0; it < 5; ++it) {
            int i   = it * 256 + tid;    // 0..1279
            int col = i / 20, c = i - col * 20;
            f16x8 v = *(const f16x8*)(w1t + (size_t)col * K_PAD + k0 + c * 8);
            f16x4 lo = { v[0], v[1], v[2], v[3] };
            f16x4 hi = { v[4], v[5], v[6], v[7] };
            *(f16x4*)(&Bs[col * PSTR + c * 8])     = lo;
            *(f16x4*)(&Bs[col * PSTR + c * 8 + 4]) = hi;
        }
        __syncthreads();
        // ---- compute: 10 K-steps, pure LDS ----
        const int abase = (wave * 16 + l16) * PSTR;
        #pragma unroll
        for (int st = 0; st < 10; ++st) {
            f16x4 a = *(const f16x4*)(&As[abase + st * 16 + l4 * 4]);
            #pragma unroll
            for (int t = 0; t < 4; ++t) {
                f16x4 b = *(const f16x4*)(&Bs[(t * 16 + l16) * PSTR + st * 16 + l4 * 4]);
                acc[t] = __builtin_amdgcn_mfma_f32_16x16x16f16(a, b, acc[t], 0, 0, 0);
            }
        }
    }

    // epilogue: h1 write + fused attention coefficients (reduce over 8 channels)
    const int wrow0 = brow0 + wave * 16;
    #pragma unroll
    for (int t = 0; t < 4; ++t) {
        const int head = t * 2 + (l16 >> 3);
        const int ch   = l16 & 7;
        const float asc = att_src1[head * 8 + ch];
        const float adc = att_dst1[head * 8 + ch];
        #pragma unroll
        for (int j = 0; j < 4; ++j) {
            int r = wrow0 + l4 * 4 + j;    // C: col = lane&15, row = (lane>>4)*4 + reg
            float ps = acc[t][j] * asc, pd = acc[t][j] * adc;
            ps += __shfl_xor(ps, 1); ps += __shfl_xor(ps, 2); ps += __shfl_xor(ps, 4);
            pd += __shfl_xor(pd, 1); pd += __shfl_xor(pd, 2); pd += __shfl_xor(pd, 4);
            if (r < N_NODES) {
                h1[(size_t)r * 64 + t * 16 + l16] = (_Float16)acc[t][j];
                if (ch == 0) {
                    a_s1[r * 8 + head] = ps;
                    a_d1[r * 8 + head] = pd;
                }
            }
        }
    }
}

// ---------------- layer-1 aggregate (defer-max + prefetch pipeline) ----------------
// 1 node / wave; lane = es*8 + h. Next edge's {idx, a_s, h1} loads issue before
// current edge's math -> gather latency overlaps compute.
__global__ __launch_bounds__(256) void k_agg1(
    const int* __restrict__ offsets, const int* __restrict__ counts,
    const int* __restrict__ sorted_src,
    const float* __restrict__ a_s1, const float* __restrict__ a_d1,
    const _Float16* __restrict__ h1, const float* __restrict__ b1,
    const float* __restrict__ w2, const float* __restrict__ att_src2,
    const float* __restrict__ att_dst2,
    _Float16* __restrict__ g, float* __restrict__ a_s2, float* __restrict__ a_d2) {
    const int lane = threadIdx.x & 63;
    const int wave = threadIdx.x >> 6;
    const int h    = lane & 7;
    const int es   = lane >> 3;
    const int n    = blockIdx.x * 4 + wave;     // 25000*4 = 100000 exact
    const int start = offsets[n];
    const int cnt   = counts[n];
    const float adn = a_d1[n * 8 + h];
    float et = a_s1[n * 8 + h] + adn;
    const float e_self = et > 0.f ? et : 0.2f * et;

    float m = e_self, denom = 0.f;
    float acc[8] = {0.f,0.f,0.f,0.f,0.f,0.f,0.f,0.f};
    if (es == 0) {                 // self-loop: exp(e_self - m) = 1
        denom = 1.f;
        f16x8 hv0 = *(const f16x8*)(h1 + (size_t)n * 64 + h * 8);
        #pragma unroll
        for (int c = 0; c < 8; ++c) acc[c] = (float)hv0[c];
    }
    int i = es;
    if (i < cnt) {
        int s = sorted_src[start + i];
        float av = a_s1[s * 8 + h];
        f16x8 hv = *(const f16x8*)(h1 + (size_t)s * 64 + h * 8);
        for (;;) {
            const int inx = i + 8;
            const bool more = inx < cnt;
            int   sn = sorted_src[start + (more ? inx : i)];
            float an = a_s1[sn * 8 + h];
            f16x8 hn = *(const f16x8*)(h1 + (size_t)sn * 64 + h * 8);
            float e = av + adn;
            e = e > 0.f ? e : 0.2f * e;
            if (e > m + 8.f) {     // rare rescale
                float sc = __expf(m - e);
                denom *= sc;
                #pragma unroll
                for (int c = 0; c < 8; ++c) acc[c] *= sc;
                m = e;
            }
            float p = __expf(e - m);
            denom += p;
            #pragma unroll
            for (int c = 0; c < 8; ++c) acc[c] += p * (float)hv[c];
            if (!more) break;
            i = inx; av = an; hv = hn;
        }
    }
    // combine 8 edge-slots per head (xor 8,16,32); m may differ after rescales
    #pragma unroll
    for (int d = 8; d < 64; d <<= 1) {
        float mo = __shfl_xor(m, d);
        float dn = __shfl_xor(denom, d);
        float mn = fmaxf(m, mo);
        float sa = __expf(m - mn), sb = __expf(mo - mn);
        denom = denom * sa + dn * sb;
        #pragma unroll
        for (int c = 0; c < 8; ++c) {
            float ao = __shfl_xor(acc[c], d);
            acc[c] = acc[c] * sa + ao * sb;
        }
        m = mn;
    }
    float inv = 1.f / (denom + 1e-16f);
    float hc[8];
    #pragma unroll
    for (int c = 0; c < 8; ++c) {
        float v = acc[c] * inv;
        v += __shfl_xor(v, 1);
        v += __shfl_xor(v, 2);
        v += __shfl_xor(v, 4);                  // mean over heads
        float o = 0.125f * v + b1[c];
        hc[c] = o > 0.f ? o : expm1f(o);        // ELU
    }
    if (lane == 0) {
        float s2 = 0.f, d2 = 0.f;
        f16x8 gr;
        #pragma unroll
        for (int j = 0; j < 7; ++j) {
            float t = 0.f;
            #pragma unroll
            for (int c = 0; c < 8; ++c) t += hc[c] * w2[c * 7 + j];
            gr[j] = (_Float16)t;
            s2 += t * att_src2[j];
            d2 += t * att_dst2[j];
        }
        gr[7] = (_Float16)0.f;
        *(f16x8*)(g + (size_t)n * 8) = gr;
        a_s2[n] = s2;
        a_d2[n] = d2;
    }
}

// ---------------- layer-2 aggregate (defer-max + prefetch) + log_softmax ----------------
__global__ __launch_bounds__(256) void k_agg2(
    const int* __restrict__ offsets, const int* __restrict__ counts,
    const int* __restrict__ sorted_src,
    const float* __restrict__ a_s2, const float* __restrict__ a_d2,
    const _Float16* __restrict__ g, const float* __restrict__ b2,
    float* __restrict__ outp) {
    const int tid  = threadIdx.x;
    const int lane = tid & 63;
    const int wave = tid >> 6;
    const int grp  = lane >> 3;
    const int s    = lane & 7;
    const int n    = blockIdx.x * 32 + wave * 8 + grp;
    const int start = offsets[n];
    const int cnt   = counts[n];
    const float adn = a_d2[n];
    float et = a_s2[n] + adn;
    const float e_self = et > 0.f ? et : 0.2f * et;

    float m = e_self, denom = 0.f;
    float acc[8] = {0.f,0.f,0.f,0.f,0.f,0.f,0.f,0.f};
    if (s == 0) {
        denom = 1.f;
        f16x8 gv0 = *(const f16x8*)(g + (size_t)n * 8);
        #pragma unroll
        for (int c = 0; c < 8; ++c) acc[c] = (float)gv0[c];
    }
    int i = s;
    if (i < cnt) {
        int sc = sorted_src[start + i];
        float av = a_s2[sc];
        f16x8 gv = *(const f16x8*)(g + (size_t)sc * 8);
        for (;;) {
            const int inx = i + 8;
            const bool more = inx < cnt;
            int   sn = sorted_src[start + (more ? inx : i)];
            float an = a_s2[sn];
            f16x8 gn = *(const f16x8*)(g + (size_t)sn * 8);
            float e = av + adn;
            e = e > 0.f ? e : 0.2f * e;
            if (e > m + 8.f) {
                float scl = __expf(m - e);
                denom *= scl;
                #pragma unroll
                for (int c = 0; c < 8; ++c) acc[c] *= scl;
                m = e;
            }
            float p = __expf(e - m);
            denom += p;
            #pragma unroll
            for (int c = 0; c < 8; ++c) acc[c] += p * (float)gv[c];
            if (!more) break;
            i = inx; av = an; gv = gn;
        }
    }
    #pragma unroll
    for (int d = 1; d < 8; d <<= 1) {
        float mo = __shfl_xor(m, d, 8);
        float dn = __shfl_xor(denom, d, 8);
        float mn = fmaxf(m, mo);
        float sa = __expf(m - mn), sb = __expf(mo - mn);
        denom = denom * sa + dn * sb;
        #pragma unroll
        for (int c = 0; c < 8; ++c) {
            float ao = __shfl_xor(acc[c], d, 8);
            acc[c] = acc[c] * sa + ao * sb;
        }
        m = mn;
    }
    float inv = 1.f / (denom + 1e-16f);
    float o[7]; float mx = -1e30f;
    #pragma unroll
    for (int c = 0; c < 7; ++c) { o[c] = acc[c] * inv + b2[c]; mx = fmaxf(mx, o[c]); }
    float se = 0.f;
    #pragma unroll
    for (int c = 0; c < 7; ++c) se += __expf(o[c] - mx);
    float ls = mx + logf(se);
    if (s < 7) outp[n * 7 + s] = o[s] - ls;
}

extern "C" void kernel_launch(void* const* d_in, const int* in_sizes, int n_in,
                              void* d_out, int out_size, void* d_ws, size_t ws_size,
                              hipStream_t stream) {
    const float* x        = (const float*)d_in[0];
    const int*   ei       = (const int*)d_in[1];
    const float* W1       = (const float*)d_in[2];
    const float* att_src1 = (const float*)d_in[3];
    const float* att_dst1 = (const float*)d_in[4];
    const float* b1       = (const float*)d_in[5];
    const float* W2       = (const float*)d_in[6];
    const float* att_src2 = (const float*)d_in[7];
    const float* att_dst2 = (const float*)d_in[8];
    const float* b2       = (const float*)d_in[9];
    const int* src = ei;
    const int* dst = ei + E_EDGES;

    char* ws = (char*)d_ws;
    size_t off = 0;
    auto alloc = [&](size_t bytes) -> char* {
        char* p = ws + off;
        off = (off + bytes + 255) & ~(size_t)255;
        return p;
    };
    _Float16* h1         = (_Float16*)alloc((size_t)N_NODES * 64 * 2);
    float*    a_s1       = (float*)   alloc((size_t)N_NODES * 8 * 4);
    float*    a_d1       = (float*)   alloc((size_t)N_NODES * 8 * 4);
    _Float16* w1t        = (_Float16*)alloc((size_t)64 * K_PAD * 2);
    int*      counts     = (int*)     alloc((size_t)N_NODES * 4);
    int*      offsets    = (int*)     alloc((size_t)N_NODES * 4);
    int*      cursor     = (int*)     alloc((size_t)N_NODES * 4);
    int*      csum       = (int*)     alloc((size_t)NCH * 4);
    int*      sorted_src = (int*)     alloc((size_t)(E_EDGES + 32) * 4);
    _Float16* gbuf       = (_Float16*)alloc((size_t)N_NODES * 8 * 2);
    float*    a_s2       = (float*)   alloc((size_t)N_NODES * 4);
    float*    a_d2       = (float*)   alloc((size_t)N_NODES * 4);
    float*    outp       = (float*)d_out;

    hipLaunchKernelGGL(k_init,    dim3(391),   dim3(256), 0, stream, W1, w1t, counts);
    hipLaunchKernelGGL(k_hist,    dim3(3125),  dim3(256), 0, stream, dst, counts);
    hipLaunchKernelGGL(k_scan_a,  dim3(NCH),   dim3(256), 0, stream, counts, csum);
    hipLaunchKernelGGL(k_scan_b,  dim3(1),     dim3(128), 0, stream, csum);
    hipLaunchKernelGGL(k_scan_c,  dim3(NCH),   dim3(256), 0, stream, counts, csum, offsets, cursor);
    hipLaunchKernelGGL(k_scatter, dim3(3125),  dim3(256), 0, stream, src, dst, cursor, sorted_src);
    hipLaunchKernelGGL(k_gemm1,   dim3(1563),  dim3(256), 0, stream, x, w1t, att_src1, att_dst1,
                       h1, a_s1, a_d1);
    hipLaunchKernelGGL(k_agg1,    dim3(25000), dim3(256), 0, stream, offsets, counts, sorted_src,
                       a_s1, a_d1, h1, b1, W2, att_src2, att_dst2, gbuf, a_s2, a_d2);
    hipLaunchKernelGGL(k_agg2,    dim3(3125),  dim3(256), 0, stream, offsets, counts, sorted_src,
                       a_s2, a_d2, gbuf, b2, outp);
}

// Round 10
// 715.887 us; speedup vs baseline: 1.0843x; 1.0843x over previous
//
#include <hip/hip_runtime.h>

#define N_NODES 100000
#define E_EDGES 3200000
#define F_IN    1433
#define K_PAD   1536   // w1t padded K (12*128)
#define NCH     98     // scan chunks of 1024
#define KPH     128    // k per LDS phase (12 phases)

typedef _Float16 f16x4 __attribute__((ext_vector_type(4)));
typedef _Float16 f16x8 __attribute__((ext_vector_type(8)));
typedef float    f32x4 __attribute__((ext_vector_type(4)));

__device__ __forceinline__ void gload_lds16(const void* g, void* l) {
    __builtin_amdgcn_global_load_lds(
        (const __attribute__((address_space(1))) unsigned int*)g,
        (__attribute__((address_space(3))) unsigned int*)l, 16, 0, 0);
}

// ---------------- init: counts=0 + W1^T fp16 [64][K_PAD] zero-padded ----------------
__global__ void k_init(const float* __restrict__ w1, _Float16* __restrict__ w1t,
                       int* __restrict__ counts) {
    int i = blockIdx.x * 256 + threadIdx.x;
    if (i < N_NODES) counts[i] = 0;
    if (i < 64 * K_PAD) {
        int n = i / K_PAD, k = i - n * K_PAD;
        float v = (k < F_IN) ? w1[(size_t)k * 64 + n] : 0.f;
        w1t[i] = (_Float16)v;
    }
}

__global__ void k_hist(const int* __restrict__ dst, int* __restrict__ counts) {
    int idx = blockIdx.x * 256 + threadIdx.x;      // 3125*256*4 = 3.2M
    int4 d4 = ((const int4*)dst)[idx];
    atomicAdd(&counts[d4.x], 1);
    atomicAdd(&counts[d4.y], 1);
    atomicAdd(&counts[d4.z], 1);
    atomicAdd(&counts[d4.w], 1);
}

// ---------------- exclusive scan of counts (chunked) ----------------
__global__ void k_scan_a(const int* __restrict__ counts, int* __restrict__ csum) {
    __shared__ int sh[256];
    int b = blockIdx.x, t = threadIdx.x;
    int s = 0;
    for (int j = 0; j < 4; ++j) {
        int idx = b * 1024 + j * 256 + t;
        if (idx < N_NODES) s += counts[idx];
    }
    sh[t] = s; __syncthreads();
    for (int off = 128; off > 0; off >>= 1) {
        if (t < off) sh[t] += sh[t + off];
        __syncthreads();
    }
    if (t == 0) csum[b] = sh[0];
}

__global__ void k_scan_b(int* __restrict__ csum) {
    __shared__ int sh[128];
    int t = threadIdx.x;
    int v = (t < NCH) ? csum[t] : 0;
    sh[t] = v; __syncthreads();
    for (int off = 1; off < 128; off <<= 1) {
        int u = (t >= off) ? sh[t - off] : 0;
        __syncthreads();
        sh[t] += u;
        __syncthreads();
    }
    if (t < NCH) csum[t] = sh[t] - v;   // exclusive
}

__global__ void k_scan_c(const int* __restrict__ counts, const int* __restrict__ csum,
                         int* __restrict__ offsets, int* __restrict__ cursor) {
    __shared__ int sh[256];
    int b = blockIdx.x, t = threadIdx.x;
    int base = b * 1024 + t * 4;
    int c0 = (base + 0 < N_NODES) ? counts[base + 0] : 0;
    int c1 = (base + 1 < N_NODES) ? counts[base + 1] : 0;
    int c2 = (base + 2 < N_NODES) ? counts[base + 2] : 0;
    int c3 = (base + 3 < N_NODES) ? counts[base + 3] : 0;
    int tot = c0 + c1 + c2 + c3;
    sh[t] = tot; __syncthreads();
    for (int off = 1; off < 256; off <<= 1) {
        int v = (t >= off) ? sh[t - off] : 0;
        __syncthreads();
        sh[t] += v;
        __syncthreads();
    }
    int excl = sh[t] - tot;
    int o = csum[b] + excl;
    if (base + 0 < N_NODES) { offsets[base + 0] = o;            cursor[base + 0] = o; }
    if (base + 1 < N_NODES) { int q = o + c0;      offsets[base + 1] = q; cursor[base + 1] = q; }
    if (base + 2 < N_NODES) { int q = o + c0 + c1; offsets[base + 2] = q; cursor[base + 2] = q; }
    if (base + 3 < N_NODES) { int q = o + c0 + c1 + c2; offsets[base + 3] = q; cursor[base + 3] = q; }
}

__global__ void k_scatter(const int* __restrict__ src, const int* __restrict__ dst,
                          int* __restrict__ cursor, int* __restrict__ sorted_src) {
    int idx = blockIdx.x * 256 + threadIdx.x;
    int4 s4 = ((const int4*)src)[idx];
    int4 d4 = ((const int4*)dst)[idx];
    int p;
    p = atomicAdd(&cursor[d4.x], 1); sorted_src[p] = s4.x;
    p = atomicAdd(&cursor[d4.y], 1); sorted_src[p] = s4.y;
    p = atomicAdd(&cursor[d4.z], 1); sorted_src[p] = s4.z;
    p = atomicAdd(&cursor[d4.w], 1); sorted_src[p] = s4.w;
}

// ---------------- GEMM1 + fused att1: h1 = x @ W1, a_s1/a_d1 ----------------
// A (fp32) and B (fp16) staged to LDS via global_load_lds (DMA, no VGPR/VALU),
// 12 K-phases of 128. Bank conflicts fixed by pre-swizzling the GLOBAL source
// chunk index (chunk ^ (row&7)) and applying the same XOR on the ds_read side.
// LDS[row][q] holds global chunk q^(row&7); read of chunk c uses slot c^(row&7).
__global__ __launch_bounds__(256) void k_gemm1(const float* __restrict__ x,
                                               const _Float16* __restrict__ w1t,
                                               const float* __restrict__ att_src1,
                                               const float* __restrict__ att_dst1,
                                               _Float16* __restrict__ h1,
                                               float* __restrict__ a_s1,
                                               float* __restrict__ a_d1) {
    __shared__ __align__(16) char AsB[64 * 512];   // 64 rows x 128 fp32 = 32 KB
    __shared__ __align__(16) char BsB[64 * 256];   // 64 cols x 128 fp16 = 16 KB
    const int tid  = threadIdx.x;
    const int lane = tid & 63;
    const int wave = tid >> 6;
    const int l16  = lane & 15;
    const int l4   = lane >> 4;
    const int brow0 = blockIdx.x * 64;

    f32x4 acc[4] = {};
    for (int ph = 0; ph < 12; ++ph) {
        __syncthreads();                 // prev phase's LDS reads done
        if (ph < 11) {
            // A: 64 rows x 32 chunks(16B fp32), source-swizzled, DMA to linear LDS
            #pragma unroll
            for (int j = 0; j < 8; ++j) {
                int p = j * 256 + tid;
                int row = p >> 5, q = p & 31;
                int qs = q ^ (row & 7);
                int grow = brow0 + row; if (grow > N_NODES - 1) grow = N_NODES - 1;
                const float* gp = x + (size_t)grow * F_IN + ph * KPH + qs * 4;
                gload_lds16(gp, AsB + j * 4096 + wave * 1024);
            }
        } else {
            // phase 11 (k 1408..1535): plain guarded staging, zero-fill k>=1433
            for (int i = tid; i < 2048; i += 256) {
                int row = i >> 5, q = i & 31;
                int qs = q ^ (row & 7);
                int grow = brow0 + row; if (grow > N_NODES - 1) grow = N_NODES - 1;
                const float* gp = x + (size_t)grow * F_IN;
                float4 v;
                #pragma unroll
                for (int jj = 0; jj < 4; ++jj) {
                    int k = 1408 + qs * 4 + jj;
                    ((float*)&v)[jj] = (k < F_IN) ? gp[k] : 0.f;
                }
                *(float4*)(AsB + row * 512 + q * 16) = v;
            }
        }
        // B: 64 cols x 16 chunks(16B fp16), source-swizzled, DMA (w1t zero-padded)
        #pragma unroll
        for (int j = 0; j < 4; ++j) {
            int p = j * 256 + tid;
            int col = p >> 4, c = p & 15;
            int cs = c ^ (col & 7);
            const _Float16* gp = w1t + (size_t)col * K_PAD + ph * KPH + cs * 8;
            gload_lds16(gp, BsB + j * 4096 + wave * 1024);
        }
        __syncthreads();                 // compiler drains vmcnt(0) here

        const int rA = wave * 16 + l16;
        const int abase = rA * 512;
        const int r7 = rA & 7;
        #pragma unroll
        for (int st = 0; st < 8; ++st) {
            float4 af = *(const float4*)(AsB + abase + ((((st << 2) + l4) ^ r7) << 4));
            f16x4 a = { (_Float16)af.x, (_Float16)af.y, (_Float16)af.z, (_Float16)af.w };
            #pragma unroll
            for (int t = 0; t < 4; ++t) {
                const int cB = t * 16 + l16;
                const int boff = cB * 256 + (((((st << 1) + (l4 >> 1)) ^ (cB & 7)) << 4))
                                 + ((l4 & 1) << 3);
                f16x4 b = *(const f16x4*)(BsB + boff);
                acc[t] = __builtin_amdgcn_mfma_f32_16x16x16f16(a, b, acc[t], 0, 0, 0);
            }
        }
    }

    // epilogue: h1 write + fused attention coefficients (reduce over 8 channels)
    const int wrow0 = brow0 + wave * 16;
    #pragma unroll
    for (int t = 0; t < 4; ++t) {
        const int head = t * 2 + (l16 >> 3);
        const int ch   = l16 & 7;
        const float asc = att_src1[head * 8 + ch];
        const float adc = att_dst1[head * 8 + ch];
        #pragma unroll
        for (int j = 0; j < 4; ++j) {
            int r = wrow0 + l4 * 4 + j;    // C: col = lane&15, row = (lane>>4)*4 + reg
            float ps = acc[t][j] * asc, pd = acc[t][j] * adc;
            ps += __shfl_xor(ps, 1); ps += __shfl_xor(ps, 2); ps += __shfl_xor(ps, 4);
            pd += __shfl_xor(pd, 1); pd += __shfl_xor(pd, 2); pd += __shfl_xor(pd, 4);
            if (r < N_NODES) {
                h1[(size_t)r * 64 + t * 16 + l16] = (_Float16)acc[t][j];
                if (ch == 0) {
                    a_s1[r * 8 + head] = ps;
                    a_d1[r * 8 + head] = pd;
                }
            }
        }
    }
}

// ---------------- layer-1 aggregate (defer-max + prefetch pipeline) ----------------
__global__ __launch_bounds__(256) void k_agg1(
    const int* __restrict__ offsets, const int* __restrict__ counts,
    const int* __restrict__ sorted_src,
    const float* __restrict__ a_s1, const float* __restrict__ a_d1,
    const _Float16* __restrict__ h1, const float* __restrict__ b1,
    const float* __restrict__ w2, const float* __restrict__ att_src2,
    const float* __restrict__ att_dst2,
    _Float16* __restrict__ g, float* __restrict__ a_s2, float* __restrict__ a_d2) {
    const int lane = threadIdx.x & 63;
    const int wave = threadIdx.x >> 6;
    const int h    = lane & 7;
    const int es   = lane >> 3;
    const int n    = blockIdx.x * 4 + wave;     // 25000*4 = 100000 exact
    const int start = offsets[n];
    const int cnt   = counts[n];
    const float adn = a_d1[n * 8 + h];
    float et = a_s1[n * 8 + h] + adn;
    const float e_self = et > 0.f ? et : 0.2f * et;

    float m = e_self, denom = 0.f;
    float acc[8] = {0.f,0.f,0.f,0.f,0.f,0.f,0.f,0.f};
    if (es == 0) {                 // self-loop: exp(e_self - m) = 1
        denom = 1.f;
        f16x8 hv0 = *(const f16x8*)(h1 + (size_t)n * 64 + h * 8);
        #pragma unroll
        for (int c = 0; c < 8; ++c) acc[c] = (float)hv0[c];
    }
    int i = es;
    if (i < cnt) {
        int s = sorted_src[start + i];
        float av = a_s1[s * 8 + h];
        f16x8 hv = *(const f16x8*)(h1 + (size_t)s * 64 + h * 8);
        for (;;) {
            const int inx = i + 8;
            const bool more = inx < cnt;
            int   sn = sorted_src[start + (more ? inx : i)];
            float an = a_s1[sn * 8 + h];
            f16x8 hn = *(const f16x8*)(h1 + (size_t)sn * 64 + h * 8);
            float e = av + adn;
            e = e > 0.f ? e : 0.2f * e;
            if (e > m + 8.f) {     // rare rescale
                float sc = __expf(m - e);
                denom *= sc;
                #pragma unroll
                for (int c = 0; c < 8; ++c) acc[c] *= sc;
                m = e;
            }
            float p = __expf(e - m);
            denom += p;
            #pragma unroll
            for (int c = 0; c < 8; ++c) acc[c] += p * (float)hv[c];
            if (!more) break;
            i = inx; av = an; hv = hn;
        }
    }
    // combine 8 edge-slots per head (xor 8,16,32); m may differ after rescales
    #pragma unroll
    for (int d = 8; d < 64; d <<= 1) {
        float mo = __shfl_xor(m, d);
        float dn = __shfl_xor(denom, d);
        float mn = fmaxf(m, mo);
        float sa = __expf(m - mn), sb = __expf(mo - mn);
        denom = denom * sa + dn * sb;
        #pragma unroll
        for (int c = 0; c < 8; ++c) {
            float ao = __shfl_xor(acc[c], d);
            acc[c] = acc[c] * sa + ao * sb;
        }
        m = mn;
    }
    float inv = 1.f / (denom + 1e-16f);
    float hc[8];
    #pragma unroll
    for (int c = 0; c < 8; ++c) {
        float v = acc[c] * inv;
        v += __shfl_xor(v, 1);
        v += __shfl_xor(v, 2);
        v += __shfl_xor(v, 4);                  // mean over heads
        float o = 0.125f * v + b1[c];
        hc[c] = o > 0.f ? o : expm1f(o);        // ELU
    }
    if (lane == 0) {
        float s2 = 0.f, d2 = 0.f;
        f16x8 gr;
        #pragma unroll
        for (int j = 0; j < 7; ++j) {
            float t = 0.f;
            #pragma unroll
            for (int c = 0; c < 8; ++c) t += hc[c] * w2[c * 7 + j];
            gr[j] = (_Float16)t;
            s2 += t * att_src2[j];
            d2 += t * att_dst2[j];
        }
        gr[7] = (_Float16)0.f;
        *(f16x8*)(g + (size_t)n * 8) = gr;
        a_s2[n] = s2;
        a_d2[n] = d2;
    }
}

// ---------------- layer-2 aggregate (defer-max + prefetch) + log_softmax ----------------
__global__ __launch_bounds__(256) void k_agg2(
    const int* __restrict__ offsets, const int* __restrict__ counts,
    const int* __restrict__ sorted_src,
    const float* __restrict__ a_s2, const float* __restrict__ a_d2,
    const _Float16* __restrict__ g, const float* __restrict__ b2,
    float* __restrict__ outp) {
    const int tid  = threadIdx.x;
    const int lane = tid & 63;
    const int wave = tid >> 6;
    const int grp  = lane >> 3;
    const int s    = lane & 7;
    const int n    = blockIdx.x * 32 + wave * 8 + grp;
    const int start = offsets[n];
    const int cnt   = counts[n];
    const float adn = a_d2[n];
    float et = a_s2[n] + adn;
    const float e_self = et > 0.f ? et : 0.2f * et;

    float m = e_self, denom = 0.f;
    float acc[8] = {0.f,0.f,0.f,0.f,0.f,0.f,0.f,0.f};
    if (s == 0) {
        denom = 1.f;
        f16x8 gv0 = *(const f16x8*)(g + (size_t)n * 8);
        #pragma unroll
        for (int c = 0; c < 8; ++c) acc[c] = (float)gv0[c];
    }
    int i = s;
    if (i < cnt) {
        int sc = sorted_src[start + i];
        float av = a_s2[sc];
        f16x8 gv = *(const f16x8*)(g + (size_t)sc * 8);
        for (;;) {
            const int inx = i + 8;
            const bool more = inx < cnt;
            int   sn = sorted_src[start + (more ? inx : i)];
            float an = a_s2[sn];
            f16x8 gn = *(const f16x8*)(g + (size_t)sn * 8);
            float e = av + adn;
            e = e > 0.f ? e : 0.2f * e;
            if (e > m + 8.f) {
                float scl = __expf(m - e);
                denom *= scl;
                #pragma unroll
                for (int c = 0; c < 8; ++c) acc[c] *= scl;
                m = e;
            }
            float p = __expf(e - m);
            denom += p;
            #pragma unroll
            for (int c = 0; c < 8; ++c) acc[c] += p * (float)gv[c];
            if (!more) break;
            i = inx; av = an; gv = gn;
        }
    }
    #pragma unroll
    for (int d = 1; d < 8; d <<= 1) {
        float mo = __shfl_xor(m, d, 8);
        float dn = __shfl_xor(denom, d, 8);
        float mn = fmaxf(m, mo);
        float sa = __expf(m - mn), sb = __expf(mo - mn);
        denom = denom * sa + dn * sb;
        #pragma unroll
        for (int c = 0; c < 8; ++c) {
            float ao = __shfl_xor(acc[c], d, 8);
            acc[c] = acc[c] * sa + ao * sb;
        }
        m = mn;
    }
    float inv = 1.f / (denom + 1e-16f);
    float o[7]; float mx = -1e30f;
    #pragma unroll
    for (int c = 0; c < 7; ++c) { o[c] = acc[c] * inv + b2[c]; mx = fmaxf(mx, o[c]); }
    float se = 0.f;
    #pragma unroll
    for (int c = 0; c < 7; ++c) se += __expf(o[c] - mx);
    float ls = mx + logf(se);
    if (s < 7) outp[n * 7 + s] = o[s] - ls;
}

extern "C" void kernel_launch(void* const* d_in, const int* in_sizes, int n_in,
                              void* d_out, int out_size, void* d_ws, size_t ws_size,
                              hipStream_t stream) {
    const float* x        = (const float*)d_in[0];
    const int*   ei       = (const int*)d_in[1];
    const float* W1       = (const float*)d_in[2];
    const float* att_src1 = (const float*)d_in[3];
    const float* att_dst1 = (const float*)d_in[4];
    const float* b1       = (const float*)d_in[5];
    const float* W2       = (const float*)d_in[6];
    const float* att_src2 = (const float*)d_in[7];
    const float* att_dst2 = (const float*)d_in[8];
    const float* b2       = (const float*)d_in[9];
    const int* src = ei;
    const int* dst = ei + E_EDGES;

    char* ws = (char*)d_ws;
    size_t off = 0;
    auto alloc = [&](size_t bytes) -> char* {
        char* p = ws + off;
        off = (off + bytes + 255) & ~(size_t)255;
        return p;
    };
    _Float16* h1         = (_Float16*)alloc((size_t)N_NODES * 64 * 2);
    float*    a_s1       = (float*)   alloc((size_t)N_NODES * 8 * 4);
    float*    a_d1       = (float*)   alloc((size_t)N_NODES * 8 * 4);
    _Float16* w1t        = (_Float16*)alloc((size_t)64 * K_PAD * 2);
    int*      counts     = (int*)     alloc((size_t)N_NODES * 4);
    int*      offsets    = (int*)     alloc((size_t)N_NODES * 4);
    int*      cursor     = (int*)     alloc((size_t)N_NODES * 4);
    int*      csum       = (int*)     alloc((size_t)NCH * 4);
    int*      sorted_src = (int*)     alloc((size_t)(E_EDGES + 32) * 4);
    _Float16* gbuf       = (_Float16*)alloc((size_t)N_NODES * 8 * 2);
    float*    a_s2       = (float*)   alloc((size_t)N_NODES * 4);
    float*    a_d2       = (float*)   alloc((size_t)N_NODES * 4);
    float*    outp       = (float*)d_out;

    hipLaunchKernelGGL(k_init,    dim3(391),   dim3(256), 0, stream, W1, w1t, counts);
    hipLaunchKernelGGL(k_hist,    dim3(3125),  dim3(256), 0, stream, dst, counts);
    hipLaunchKernelGGL(k_scan_a,  dim3(NCH),   dim3(256), 0, stream, counts, csum);
    hipLaunchKernelGGL(k_scan_b,  dim3(1),     dim3(128), 0, stream, csum);
    hipLaunchKernelGGL(k_scan_c,  dim3(NCH),   dim3(256), 0, stream, counts, csum, offsets, cursor);
    hipLaunchKernelGGL(k_scatter, dim3(3125),  dim3(256), 0, stream, src, dst, cursor, sorted_src);
    hipLaunchKernelGGL(k_gemm1,   dim3(1563),  dim3(256), 0, stream, x, w1t, att_src1, att_dst1,
                       h1, a_s1, a_d1);
    hipLaunchKernelGGL(k_agg1,    dim3(25000), dim3(256), 0, stream, offsets, counts, sorted_src,
                       a_s1, a_d1, h1, b1, W2, att_src2, att_dst2, gbuf, a_s2, a_d2);
    hipLaunchKernelGGL(k_agg2,    dim3(3125),  dim3(256), 0, stream, offsets, counts, sorted_src,
                       a_s2, a_d2, gbuf, b2, outp);
}

// Round 11
// 670.921 us; speedup vs baseline: 1.1570x; 1.0670x over previous
//
#include <hip/hip_runtime.h>

#define N_NODES 100000
#define E_EDGES 3200000
#define F_IN    1433
#define K_PAD   1472   // w1t padded K (23*64)
#define NCH     98     // scan chunks of 1024
#define KPH     64     // k per phase; 22 DMA phases + guarded tail

typedef _Float16 f16x4 __attribute__((ext_vector_type(4)));
typedef _Float16 f16x8 __attribute__((ext_vector_type(8)));
typedef float    f32x4 __attribute__((ext_vector_type(4)));

__device__ __forceinline__ void gload_lds16(const void* g, void* l) {
    __builtin_amdgcn_global_load_lds(
        (const __attribute__((address_space(1))) unsigned int*)g,
        (__attribute__((address_space(3))) unsigned int*)l, 16, 0, 0);
}

// ---------------- init: counts=0 + W1^T fp16 [64][K_PAD] zero-padded ----------------
__global__ void k_init(const float* __restrict__ w1, _Float16* __restrict__ w1t,
                       int* __restrict__ counts) {
    int i = blockIdx.x * 256 + threadIdx.x;
    if (i < N_NODES) counts[i] = 0;
    if (i < 64 * K_PAD) {
        int n = i / K_PAD, k = i - n * K_PAD;
        float v = (k < F_IN) ? w1[(size_t)k * 64 + n] : 0.f;
        w1t[i] = (_Float16)v;
    }
}

__global__ void k_hist(const int* __restrict__ dst, int* __restrict__ counts) {
    int idx = blockIdx.x * 256 + threadIdx.x;      // 3125*256*4 = 3.2M
    int4 d4 = ((const int4*)dst)[idx];
    atomicAdd(&counts[d4.x], 1);
    atomicAdd(&counts[d4.y], 1);
    atomicAdd(&counts[d4.z], 1);
    atomicAdd(&counts[d4.w], 1);
}

// ---------------- exclusive scan of counts (chunked) ----------------
__global__ void k_scan_a(const int* __restrict__ counts, int* __restrict__ csum) {
    __shared__ int sh[256];
    int b = blockIdx.x, t = threadIdx.x;
    int s = 0;
    for (int j = 0; j < 4; ++j) {
        int idx = b * 1024 + j * 256 + t;
        if (idx < N_NODES) s += counts[idx];
    }
    sh[t] = s; __syncthreads();
    for (int off = 128; off > 0; off >>= 1) {
        if (t < off) sh[t] += sh[t + off];
        __syncthreads();
    }
    if (t == 0) csum[b] = sh[0];
}

__global__ void k_scan_b(int* __restrict__ csum) {
    __shared__ int sh[128];
    int t = threadIdx.x;
    int v = (t < NCH) ? csum[t] : 0;
    sh[t] = v; __syncthreads();
    for (int off = 1; off < 128; off <<= 1) {
        int u = (t >= off) ? sh[t - off] : 0;
        __syncthreads();
        sh[t] += u;
        __syncthreads();
    }
    if (t < NCH) csum[t] = sh[t] - v;   // exclusive
}

__global__ void k_scan_c(const int* __restrict__ counts, const int* __restrict__ csum,
                         int* __restrict__ offsets, int* __restrict__ cursor) {
    __shared__ int sh[256];
    int b = blockIdx.x, t = threadIdx.x;
    int base = b * 1024 + t * 4;
    int c0 = (base + 0 < N_NODES) ? counts[base + 0] : 0;
    int c1 = (base + 1 < N_NODES) ? counts[base + 1] : 0;
    int c2 = (base + 2 < N_NODES) ? counts[base + 2] : 0;
    int c3 = (base + 3 < N_NODES) ? counts[base + 3] : 0;
    int tot = c0 + c1 + c2 + c3;
    sh[t] = tot; __syncthreads();
    for (int off = 1; off < 256; off <<= 1) {
        int v = (t >= off) ? sh[t - off] : 0;
        __syncthreads();
        sh[t] += v;
        __syncthreads();
    }
    int excl = sh[t] - tot;
    int o = csum[b] + excl;
    if (base + 0 < N_NODES) { offsets[base + 0] = o;            cursor[base + 0] = o; }
    if (base + 1 < N_NODES) { int q = o + c0;      offsets[base + 1] = q; cursor[base + 1] = q; }
    if (base + 2 < N_NODES) { int q = o + c0 + c1; offsets[base + 2] = q; cursor[base + 2] = q; }
    if (base + 3 < N_NODES) { int q = o + c0 + c1 + c2; offsets[base + 3] = q; cursor[base + 3] = q; }
}

__global__ void k_scatter(const int* __restrict__ src, const int* __restrict__ dst,
                          int* __restrict__ cursor, int* __restrict__ sorted_src) {
    int idx = blockIdx.x * 256 + threadIdx.x;
    int4 s4 = ((const int4*)src)[idx];
    int4 d4 = ((const int4*)dst)[idx];
    int p;
    p = atomicAdd(&cursor[d4.x], 1); sorted_src[p] = s4.x;
    p = atomicAdd(&cursor[d4.y], 1); sorted_src[p] = s4.y;
    p = atomicAdd(&cursor[d4.z], 1); sorted_src[p] = s4.z;
    p = atomicAdd(&cursor[d4.w], 1); sorted_src[p] = s4.w;
}

// ---------------- GEMM1 + fused att1: h1 = x @ W1, a_s1/a_d1 ----------------
// Double-buffered global_load_lds pipeline (T3-minimal, m97 structure):
// issue phase-(p+1) DMAs into buf^1 BEFORE computing phase p from buf;
// the end-of-phase barrier's vmcnt(0) drain overlaps with compute.
// A fp32 (swizzled chunks q^(row&7), 16/row), B fp16 (c^(col&7), 8/col).
__global__ __launch_bounds__(256) void k_gemm1(const float* __restrict__ x,
                                               const _Float16* __restrict__ w1t,
                                               const float* __restrict__ att_src1,
                                               const float* __restrict__ att_dst1,
                                               _Float16* __restrict__ h1,
                                               float* __restrict__ a_s1,
                                               float* __restrict__ a_d1) {
    __shared__ __align__(16) char AsB[2][64 * 256];   // 16 KB per buffer (fp32)
    __shared__ __align__(16) char BsB[2][64 * 128];   //  8 KB per buffer (fp16)
    const int tid  = threadIdx.x;
    const int lane = tid & 63;
    const int wave = tid >> 6;
    const int l16  = lane & 15;
    const int l4   = lane >> 4;
    const int brow0 = blockIdx.x * 64;

    f32x4 acc[4] = {};

    // DMA staging of one 64x64 A phase (4 issues/thread) + B phase (2 issues/thread)
    auto stageA = [&](int buf, int ph) {
        #pragma unroll
        for (int j = 0; j < 4; ++j) {
            int p = j * 256 + tid;
            int row = p >> 4, q = p & 15;
            int qs = q ^ (row & 7);
            int grow = brow0 + row; if (grow > N_NODES - 1) grow = N_NODES - 1;
            const float* gp = x + (size_t)grow * F_IN + ph * KPH + qs * 4;
            gload_lds16(gp, AsB[buf] + j * 4096 + wave * 1024);
        }
    };
    auto stageB = [&](int buf, int ph) {
        #pragma unroll
        for (int j = 0; j < 2; ++j) {
            int p = j * 256 + tid;
            int col = p >> 3, c = p & 7;
            int cs = c ^ (col & 7);
            const _Float16* gp = w1t + (size_t)col * K_PAD + ph * KPH + cs * 8;
            gload_lds16(gp, BsB[buf] + j * 4096 + wave * 1024);
        }
    };
    // tail phase 22 (k 1408..1471): guarded plain staging, zero-fill k>=1433
    auto stageTailA = [&](int buf) {
        for (int i = tid; i < 1024; i += 256) {
            int row = i >> 4, q = i & 15;
            int qs = q ^ (row & 7);
            int grow = brow0 + row; if (grow > N_NODES - 1) grow = N_NODES - 1;
            const float* gp = x + (size_t)grow * F_IN;
            float4 v;
            #pragma unroll
            for (int jj = 0; jj < 4; ++jj) {
                int k = 1408 + qs * 4 + jj;
                ((float*)&v)[jj] = (k < F_IN) ? gp[k] : 0.f;
            }
            *(float4*)(AsB[buf] + row * 256 + q * 16) = v;
        }
    };
    auto compute = [&](int buf) {
        const int rA = wave * 16 + l16;
        const char* Ab = AsB[buf] + rA * 256;
        const int r7 = rA & 7;
        #pragma unroll
        for (int st = 0; st < 4; ++st) {
            float4 af = *(const float4*)(Ab + ((((st << 2) + l4) ^ r7) << 4));
            f16x4 a = { (_Float16)af.x, (_Float16)af.y, (_Float16)af.z, (_Float16)af.w };
            #pragma unroll
            for (int t = 0; t < 4; ++t) {
                const int cB = t * 16 + l16;
                const int chunk = (st << 1) + (l4 >> 1);
                const int boff = cB * 128 + ((chunk ^ (cB & 7)) << 4) + ((l4 & 1) << 3);
                f16x4 b = *(const f16x4*)(BsB[buf] + boff);
                acc[t] = __builtin_amdgcn_mfma_f32_16x16x16f16(a, b, acc[t], 0, 0, 0);
            }
        }
    };

    stageA(0, 0); stageB(0, 0);
    __syncthreads();                       // buf0 ready
    int cur = 0;
    for (int ph = 0; ph < 22; ++ph) {
        if (ph + 1 < 22) { stageA(cur ^ 1, ph + 1); stageB(cur ^ 1, ph + 1); }
        else             { stageTailA(cur ^ 1);     stageB(cur ^ 1, 22);     }
        compute(cur);
        __syncthreads();                   // drains vmcnt(0): next buffer ready
        cur ^= 1;
    }
    compute(cur);                          // phase 22

    // epilogue: h1 write + fused attention coefficients (reduce over 8 channels)
    const int wrow0 = brow0 + wave * 16;
    #pragma unroll
    for (int t = 0; t < 4; ++t) {
        const int head = t * 2 + (l16 >> 3);
        const int ch   = l16 & 7;
        const float asc = att_src1[head * 8 + ch];
        const float adc = att_dst1[head * 8 + ch];
        #pragma unroll
        for (int j = 0; j < 4; ++j) {
            int r = wrow0 + l4 * 4 + j;    // C: col = lane&15, row = (lane>>4)*4 + reg
            float ps = acc[t][j] * asc, pd = acc[t][j] * adc;
            ps += __shfl_xor(ps, 1); ps += __shfl_xor(ps, 2); ps += __shfl_xor(ps, 4);
            pd += __shfl_xor(pd, 1); pd += __shfl_xor(pd, 2); pd += __shfl_xor(pd, 4);
            if (r < N_NODES) {
                h1[(size_t)r * 64 + t * 16 + l16] = (_Float16)acc[t][j];
                if (ch == 0) {
                    a_s1[r * 8 + head] = ps;
                    a_d1[r * 8 + head] = pd;
                }
            }
        }
    }
}

// ---------------- layer-1 aggregate (defer-max + prefetch pipeline) ----------------
__global__ __launch_bounds__(256) void k_agg1(
    const int* __restrict__ offsets, const int* __restrict__ counts,
    const int* __restrict__ sorted_src,
    const float* __restrict__ a_s1, const float* __restrict__ a_d1,
    const _Float16* __restrict__ h1, const float* __restrict__ b1,
    const float* __restrict__ w2, const float* __restrict__ att_src2,
    const float* __restrict__ att_dst2,
    _Float16* __restrict__ g, float* __restrict__ a_s2, float* __restrict__ a_d2) {
    const int lane = threadIdx.x & 63;
    const int wave = threadIdx.x >> 6;
    const int h    = lane & 7;
    const int es   = lane >> 3;
    const int n    = blockIdx.x * 4 + wave;     // 25000*4 = 100000 exact
    const int start = offsets[n];
    const int cnt   = counts[n];
    const float adn = a_d1[n * 8 + h];
    float et = a_s1[n * 8 + h] + adn;
    const float e_self = et > 0.f ? et : 0.2f * et;

    float m = e_self, denom = 0.f;
    float acc[8] = {0.f,0.f,0.f,0.f,0.f,0.f,0.f,0.f};
    if (es == 0) {                 // self-loop: exp(e_self - m) = 1
        denom = 1.f;
        f16x8 hv0 = *(const f16x8*)(h1 + (size_t)n * 64 + h * 8);
        #pragma unroll
        for (int c = 0; c < 8; ++c) acc[c] = (float)hv0[c];
    }
    int i = es;
    if (i < cnt) {
        int s = sorted_src[start + i];
        float av = a_s1[s * 8 + h];
        f16x8 hv = *(const f16x8*)(h1 + (size_t)s * 64 + h * 8);
        for (;;) {
            const int inx = i + 8;
            const bool more = inx < cnt;
            int   sn = sorted_src[start + (more ? inx : i)];
            float an = a_s1[sn * 8 + h];
            f16x8 hn = *(const f16x8*)(h1 + (size_t)sn * 64 + h * 8);
            float e = av + adn;
            e = e > 0.f ? e : 0.2f * e;
            if (e > m + 8.f) {     // rare rescale
                float sc = __expf(m - e);
                denom *= sc;
                #pragma unroll
                for (int c = 0; c < 8; ++c) acc[c] *= sc;
                m = e;
            }
            float p = __expf(e - m);
            denom += p;
            #pragma unroll
            for (int c = 0; c < 8; ++c) acc[c] += p * (float)hv[c];
            if (!more) break;
            i = inx; av = an; hv = hn;
        }
    }
    // combine 8 edge-slots per head (xor 8,16,32); m may differ after rescales
    #pragma unroll
    for (int d = 8; d < 64; d <<= 1) {
        float mo = __shfl_xor(m, d);
        float dn = __shfl_xor(denom, d);
        float mn = fmaxf(m, mo);
        float sa = __expf(m - mn), sb = __expf(mo - mn);
        denom = denom * sa + dn * sb;
        #pragma unroll
        for (int c = 0; c < 8; ++c) {
            float ao = __shfl_xor(acc[c], d);
            acc[c] = acc[c] * sa + ao * sb;
        }
        m = mn;
    }
    float inv = 1.f / (denom + 1e-16f);
    float hc[8];
    #pragma unroll
    for (int c = 0; c < 8; ++c) {
        float v = acc[c] * inv;
        v += __shfl_xor(v, 1);
        v += __shfl_xor(v, 2);
        v += __shfl_xor(v, 4);                  // mean over heads
        float o = 0.125f * v + b1[c];
        hc[c] = o > 0.f ? o : expm1f(o);        // ELU
    }
    if (lane == 0) {
        float s2 = 0.f, d2 = 0.f;
        f16x8 gr;
        #pragma unroll
        for (int j = 0; j < 7; ++j) {
            float t = 0.f;
            #pragma unroll
            for (int c = 0; c < 8; ++c) t += hc[c] * w2[c * 7 + j];
            gr[j] = (_Float16)t;
            s2 += t * att_src2[j];
            d2 += t * att_dst2[j];
        }
        gr[7] = (_Float16)0.f;
        *(f16x8*)(g + (size_t)n * 8) = gr;
        a_s2[n] = s2;
        a_d2[n] = d2;
    }
}

// ---------------- layer-2 aggregate (defer-max + prefetch) + log_softmax ----------------
__global__ __launch_bounds__(256) void k_agg2(
    const int* __restrict__ offsets, const int* __restrict__ counts,
    const int* __restrict__ sorted_src,
    const float* __restrict__ a_s2, const float* __restrict__ a_d2,
    const _Float16* __restrict__ g, const float* __restrict__ b2,
    float* __restrict__ outp) {
    const int tid  = threadIdx.x;
    const int lane = tid & 63;
    const int wave = tid >> 6;
    const int grp  = lane >> 3;
    const int s    = lane & 7;
    const int n    = blockIdx.x * 32 + wave * 8 + grp;
    const int start = offsets[n];
    const int cnt   = counts[n];
    const float adn = a_d2[n];
    float et = a_s2[n] + adn;
    const float e_self = et > 0.f ? et : 0.2f * et;

    float m = e_self, denom = 0.f;
    float acc[8] = {0.f,0.f,0.f,0.f,0.f,0.f,0.f,0.f};
    if (s == 0) {
        denom = 1.f;
        f16x8 gv0 = *(const f16x8*)(g + (size_t)n * 8);
        #pragma unroll
        for (int c = 0; c < 8; ++c) acc[c] = (float)gv0[c];
    }
    int i = s;
    if (i < cnt) {
        int sc = sorted_src[start + i];
        float av = a_s2[sc];
        f16x8 gv = *(const f16x8*)(g + (size_t)sc * 8);
        for (;;) {
            const int inx = i + 8;
            const bool more = inx < cnt;
            int   sn = sorted_src[start + (more ? inx : i)];
            float an = a_s2[sn];
            f16x8 gn = *(const f16x8*)(g + (size_t)sn * 8);
            float e = av + adn;
            e = e > 0.f ? e : 0.2f * e;
            if (e > m + 8.f) {
                float scl = __expf(m - e);
                denom *= scl;
                #pragma unroll
                for (int c = 0; c < 8; ++c) acc[c] *= scl;
                m = e;
            }
            float p = __expf(e - m);
            denom += p;
            #pragma unroll
            for (int c = 0; c < 8; ++c) acc[c] += p * (float)gv[c];
            if (!more) break;
            i = inx; av = an; gv = gn;
        }
    }
    #pragma unroll
    for (int d = 1; d < 8; d <<= 1) {
        float mo = __shfl_xor(m, d, 8);
        float dn = __shfl_xor(denom, d, 8);
        float mn = fmaxf(m, mo);
        float sa = __expf(m - mn), sb = __expf(mo - mn);
        denom = denom * sa + dn * sb;
        #pragma unroll
        for (int c = 0; c < 8; ++c) {
            float ao = __shfl_xor(acc[c], d, 8);
            acc[c] = acc[c] * sa + ao * sb;
        }
        m = mn;
    }
    float inv = 1.f / (denom + 1e-16f);
    float o[7]; float mx = -1e30f;
    #pragma unroll
    for (int c = 0; c < 7; ++c) { o[c] = acc[c] * inv + b2[c]; mx = fmaxf(mx, o[c]); }
    float se = 0.f;
    #pragma unroll
    for (int c = 0; c < 7; ++c) se += __expf(o[c] - mx);
    float ls = mx + logf(se);
    if (s < 7) outp[n * 7 + s] = o[s] - ls;
}

extern "C" void kernel_launch(void* const* d_in, const int* in_sizes, int n_in,
                              void* d_out, int out_size, void* d_ws, size_t ws_size,
                              hipStream_t stream) {
    const float* x        = (const float*)d_in[0];
    const int*   ei       = (const int*)d_in[1];
    const float* W1       = (const float*)d_in[2];
    const float* att_src1 = (const float*)d_in[3];
    const float* att_dst1 = (const float*)d_in[4];
    const float* b1       = (const float*)d_in[5];
    const float* W2       = (const float*)d_in[6];
    const float* att_src2 = (const float*)d_in[7];
    const float* att_dst2 = (const float*)d_in[8];
    const float* b2       = (const float*)d_in[9];
    const int* src = ei;
    const int* dst = ei + E_EDGES;

    char* ws = (char*)d_ws;
    size_t off = 0;
    auto alloc = [&](size_t bytes) -> char* {
        char* p = ws + off;
        off = (off + bytes + 255) & ~(size_t)255;
        return p;
    };
    _Float16* h1         = (_Float16*)alloc((size_t)N_NODES * 64 * 2);
    float*    a_s1       = (float*)   alloc((size_t)N_NODES * 8 * 4);
    float*    a_d1       = (float*)   alloc((size_t)N_NODES * 8 * 4);
    _Float16* w1t        = (_Float16*)alloc((size_t)64 * K_PAD * 2);
    int*      counts     = (int*)     alloc((size_t)N_NODES * 4);
    int*      offsets    = (int*)     alloc((size_t)N_NODES * 4);
    int*      cursor     = (int*)     alloc((size_t)N_NODES * 4);
    int*      csum       = (int*)     alloc((size_t)NCH * 4);
    int*      sorted_src = (int*)     alloc((size_t)(E_EDGES + 32) * 4);
    _Float16* gbuf       = (_Float16*)alloc((size_t)N_NODES * 8 * 2);
    float*    a_s2       = (float*)   alloc((size_t)N_NODES * 4);
    float*    a_d2       = (float*)   alloc((size_t)N_NODES * 4);
    float*    outp       = (float*)d_out;

    hipLaunchKernelGGL(k_init,    dim3(391),   dim3(256), 0, stream, W1, w1t, counts);
    hipLaunchKernelGGL(k_hist,    dim3(3125),  dim3(256), 0, stream, dst, counts);
    hipLaunchKernelGGL(k_scan_a,  dim3(NCH),   dim3(256), 0, stream, counts, csum);
    hipLaunchKernelGGL(k_scan_b,  dim3(1),     dim3(128), 0, stream, csum);
    hipLaunchKernelGGL(k_scan_c,  dim3(NCH),   dim3(256), 0, stream, counts, csum, offsets, cursor);
    hipLaunchKernelGGL(k_scatter, dim3(3125),  dim3(256), 0, stream, src, dst, cursor, sorted_src);
    hipLaunchKernelGGL(k_gemm1,   dim3(1563),  dim3(256), 0, stream, x, w1t, att_src1, att_dst1,
                       h1, a_s1, a_d1);
    hipLaunchKernelGGL(k_agg1,    dim3(25000), dim3(256), 0, stream, offsets, counts, sorted_src,
                       a_s1, a_d1, h1, b1, W2, att_src2, att_dst2, gbuf, a_s2, a_d2);
    hipLaunchKernelGGL(k_agg2,    dim3(3125),  dim3(256), 0, stream, offsets, counts, sorted_src,
                       a_s2, a_d2, gbuf, b2, outp);
}

// Round 12
// 568.966 us; speedup vs baseline: 1.3643x; 1.1792x over previous
//
#include <hip/hip_runtime.h>

#define N_NODES 100000
#define E_EDGES 3200000
#define F_IN    1433
#define K_PAD   1472   // w1t padded K (23*64)
#define NCH     98     // scan chunks of 1024
#define KPH     64     // k per phase; 22 DMA phases + guarded tail
#define GEMM_BLOCKS 1563

typedef _Float16 f16x4 __attribute__((ext_vector_type(4)));
typedef _Float16 f16x8 __attribute__((ext_vector_type(8)));
typedef float    f32x4 __attribute__((ext_vector_type(4)));

__device__ __forceinline__ void gload_lds16(const void* g, void* l) {
    __builtin_amdgcn_global_load_lds(
        (const __attribute__((address_space(1))) unsigned int*)g,
        (__attribute__((address_space(3))) unsigned int*)l, 16, 0, 0);
}

// ---------------- init: counts=0 + W1^T fp16 [64][K_PAD] zero-padded ----------------
__global__ void k_init(const float* __restrict__ w1, _Float16* __restrict__ w1t,
                       int* __restrict__ counts) {
    int i = blockIdx.x * 256 + threadIdx.x;
    if (i < N_NODES) counts[i] = 0;
    if (i < 64 * K_PAD) {
        int n = i / K_PAD, k = i - n * K_PAD;
        float v = (k < F_IN) ? w1[(size_t)k * 64 + n] : 0.f;
        w1t[i] = (_Float16)v;
    }
}

__global__ void k_hist(const int* __restrict__ dst, int* __restrict__ counts) {
    int idx = blockIdx.x * 256 + threadIdx.x;      // 3125*256*4 = 3.2M
    int4 d4 = ((const int4*)dst)[idx];
    atomicAdd(&counts[d4.x], 1);
    atomicAdd(&counts[d4.y], 1);
    atomicAdd(&counts[d4.z], 1);
    atomicAdd(&counts[d4.w], 1);
}

// ---------------- exclusive scan of counts (chunked) ----------------
__global__ void k_scan_a(const int* __restrict__ counts, int* __restrict__ csum) {
    __shared__ int sh[256];
    int b = blockIdx.x, t = threadIdx.x;
    int s = 0;
    for (int j = 0; j < 4; ++j) {
        int idx = b * 1024 + j * 256 + t;
        if (idx < N_NODES) s += counts[idx];
    }
    sh[t] = s; __syncthreads();
    for (int off = 128; off > 0; off >>= 1) {
        if (t < off) sh[t] += sh[t + off];
        __syncthreads();
    }
    if (t == 0) csum[b] = sh[0];
}

__global__ void k_scan_b(int* __restrict__ csum) {
    __shared__ int sh[128];
    int t = threadIdx.x;
    int v = (t < NCH) ? csum[t] : 0;
    sh[t] = v; __syncthreads();
    for (int off = 1; off < 128; off <<= 1) {
        int u = (t >= off) ? sh[t - off] : 0;
        __syncthreads();
        sh[t] += u;
        __syncthreads();
    }
    if (t < NCH) csum[t] = sh[t] - v;   // exclusive
}

__global__ void k_scan_c(const int* __restrict__ counts, const int* __restrict__ csum,
                         int* __restrict__ offsets, int* __restrict__ cursor) {
    __shared__ int sh[256];
    int b = blockIdx.x, t = threadIdx.x;
    int base = b * 1024 + t * 4;
    int c0 = (base + 0 < N_NODES) ? counts[base + 0] : 0;
    int c1 = (base + 1 < N_NODES) ? counts[base + 1] : 0;
    int c2 = (base + 2 < N_NODES) ? counts[base + 2] : 0;
    int c3 = (base + 3 < N_NODES) ? counts[base + 3] : 0;
    int tot = c0 + c1 + c2 + c3;
    sh[t] = tot; __syncthreads();
    for (int off = 1; off < 256; off <<= 1) {
        int v = (t >= off) ? sh[t - off] : 0;
        __syncthreads();
        sh[t] += v;
        __syncthreads();
    }
    int excl = sh[t] - tot;
    int o = csum[b] + excl;
    if (base + 0 < N_NODES) { offsets[base + 0] = o;            cursor[base + 0] = o; }
    if (base + 1 < N_NODES) { int q = o + c0;      offsets[base + 1] = q; cursor[base + 1] = q; }
    if (base + 2 < N_NODES) { int q = o + c0 + c1; offsets[base + 2] = q; cursor[base + 2] = q; }
    if (base + 3 < N_NODES) { int q = o + c0 + c1 + c2; offsets[base + 3] = q; cursor[base + 3] = q; }
}

// ---------------- FUSED: gemm1(+att1) blocks [0,1563) | scatter blocks [1563,4688) ----------------
// gemm1: double-buffered global_load_lds pipeline (unchanged from r11, verified).
// scatter is independent of gemm1 (needs cursor from scan_c; gemm needs x/w1t),
// so its ~70us hides under the DMA-bound gemm span.
__global__ __launch_bounds__(256) void k_gemm_scat(const float* __restrict__ x,
                                                   const _Float16* __restrict__ w1t,
                                                   const float* __restrict__ att_src1,
                                                   const float* __restrict__ att_dst1,
                                                   _Float16* __restrict__ h1,
                                                   float* __restrict__ a_s1,
                                                   float* __restrict__ a_d1,
                                                   const int* __restrict__ src,
                                                   const int* __restrict__ dst,
                                                   int* __restrict__ cursor,
                                                   int* __restrict__ sorted_src) {
    __shared__ __align__(16) char AsB[2][64 * 256];   // 16 KB per buffer (fp32)
    __shared__ __align__(16) char BsB[2][64 * 128];   //  8 KB per buffer (fp16)
    const int tid = threadIdx.x;

    if (blockIdx.x >= GEMM_BLOCKS) {
        // ---------------- scatter role ----------------
        int idx = (blockIdx.x - GEMM_BLOCKS) * 256 + tid;
        int4 s4 = ((const int4*)src)[idx];
        int4 d4 = ((const int4*)dst)[idx];
        int p;
        p = atomicAdd(&cursor[d4.x], 1); sorted_src[p] = s4.x;
        p = atomicAdd(&cursor[d4.y], 1); sorted_src[p] = s4.y;
        p = atomicAdd(&cursor[d4.z], 1); sorted_src[p] = s4.z;
        p = atomicAdd(&cursor[d4.w], 1); sorted_src[p] = s4.w;
        return;
    }

    // ---------------- gemm1 role ----------------
    const int lane = tid & 63;
    const int wave = tid >> 6;
    const int l16  = lane & 15;
    const int l4   = lane >> 4;
    const int brow0 = blockIdx.x * 64;

    f32x4 acc[4] = {};

    auto stageA = [&](int buf, int ph) {
        #pragma unroll
        for (int j = 0; j < 4; ++j) {
            int p = j * 256 + tid;
            int row = p >> 4, q = p & 15;
            int qs = q ^ (row & 7);
            int grow = brow0 + row; if (grow > N_NODES - 1) grow = N_NODES - 1;
            const float* gp = x + (size_t)grow * F_IN + ph * KPH + qs * 4;
            gload_lds16(gp, AsB[buf] + j * 4096 + wave * 1024);
        }
    };
    auto stageB = [&](int buf, int ph) {
        #pragma unroll
        for (int j = 0; j < 2; ++j) {
            int p = j * 256 + tid;
            int col = p >> 3, c = p & 7;
            int cs = c ^ (col & 7);
            const _Float16* gp = w1t + (size_t)col * K_PAD + ph * KPH + cs * 8;
            gload_lds16(gp, BsB[buf] + j * 4096 + wave * 1024);
        }
    };
    auto stageTailA = [&](int buf) {
        for (int i = tid; i < 1024; i += 256) {
            int row = i >> 4, q = i & 15;
            int qs = q ^ (row & 7);
            int grow = brow0 + row; if (grow > N_NODES - 1) grow = N_NODES - 1;
            const float* gp = x + (size_t)grow * F_IN;
            float4 v;
            #pragma unroll
            for (int jj = 0; jj < 4; ++jj) {
                int k = 1408 + qs * 4 + jj;
                ((float*)&v)[jj] = (k < F_IN) ? gp[k] : 0.f;
            }
            *(float4*)(AsB[buf] + row * 256 + q * 16) = v;
        }
    };
    auto compute = [&](int buf) {
        const int rA = wave * 16 + l16;
        const char* Ab = AsB[buf] + rA * 256;
        const int r7 = rA & 7;
        #pragma unroll
        for (int st = 0; st < 4; ++st) {
            float4 af = *(const float4*)(Ab + ((((st << 2) + l4) ^ r7) << 4));
            f16x4 a = { (_Float16)af.x, (_Float16)af.y, (_Float16)af.z, (_Float16)af.w };
            #pragma unroll
            for (int t = 0; t < 4; ++t) {
                const int cB = t * 16 + l16;
                const int chunk = (st << 1) + (l4 >> 1);
                const int boff = cB * 128 + ((chunk ^ (cB & 7)) << 4) + ((l4 & 1) << 3);
                f16x4 b = *(const f16x4*)(BsB[buf] + boff);
                acc[t] = __builtin_amdgcn_mfma_f32_16x16x16f16(a, b, acc[t], 0, 0, 0);
            }
        }
    };

    stageA(0, 0); stageB(0, 0);
    __syncthreads();
    int cur = 0;
    for (int ph = 0; ph < 22; ++ph) {
        if (ph + 1 < 22) { stageA(cur ^ 1, ph + 1); stageB(cur ^ 1, ph + 1); }
        else             { stageTailA(cur ^ 1);     stageB(cur ^ 1, 22);     }
        compute(cur);
        __syncthreads();
        cur ^= 1;
    }
    compute(cur);

    const int wrow0 = brow0 + wave * 16;
    #pragma unroll
    for (int t = 0; t < 4; ++t) {
        const int head = t * 2 + (l16 >> 3);
        const int ch   = l16 & 7;
        const float asc = att_src1[head * 8 + ch];
        const float adc = att_dst1[head * 8 + ch];
        #pragma unroll
        for (int j = 0; j < 4; ++j) {
            int r = wrow0 + l4 * 4 + j;    // C: col = lane&15, row = (lane>>4)*4 + reg
            float ps = acc[t][j] * asc, pd = acc[t][j] * adc;
            ps += __shfl_xor(ps, 1); ps += __shfl_xor(ps, 2); ps += __shfl_xor(ps, 4);
            pd += __shfl_xor(pd, 1); pd += __shfl_xor(pd, 2); pd += __shfl_xor(pd, 4);
            if (r < N_NODES) {
                h1[(size_t)r * 64 + t * 16 + l16] = (_Float16)acc[t][j];
                if (ch == 0) {
                    a_s1[r * 8 + head] = ps;
                    a_d1[r * 8 + head] = pd;
                }
            }
        }
    }
}

// ---------------- layer-1 aggregate (defer-max, 4-deep gather batching) ----------------
// 1 node / wave; lane = es*8 + h. Per round, all 4 edges' {idx, a_s, h1} gathers
// are issued before any math -> 4 independent latency chains in flight.
__global__ __launch_bounds__(256) void k_agg1(
    const int* __restrict__ offsets, const int* __restrict__ counts,
    const int* __restrict__ sorted_src,
    const float* __restrict__ a_s1, const float* __restrict__ a_d1,
    const _Float16* __restrict__ h1, const float* __restrict__ b1,
    const float* __restrict__ w2, const float* __restrict__ att_src2,
    const float* __restrict__ att_dst2,
    _Float16* __restrict__ g, float* __restrict__ a_s2, float* __restrict__ a_d2) {
    const int lane = threadIdx.x & 63;
    const int wave = threadIdx.x >> 6;
    const int h    = lane & 7;
    const int es   = lane >> 3;
    const int n    = blockIdx.x * 4 + wave;     // 25000*4 = 100000 exact
    const int start = offsets[n];
    const int cnt   = counts[n];
    const float adn = a_d1[n * 8 + h];
    float et = a_s1[n * 8 + h] + adn;
    const float e_self = et > 0.f ? et : 0.2f * et;

    float m = e_self, denom = 0.f;
    float acc[8] = {0.f,0.f,0.f,0.f,0.f,0.f,0.f,0.f};
    if (es == 0) {                 // self-loop: exp(e_self - m) = 1
        denom = 1.f;
        f16x8 hv0 = *(const f16x8*)(h1 + (size_t)n * 64 + h * 8);
        #pragma unroll
        for (int c = 0; c < 8; ++c) acc[c] = (float)hv0[c];
    }
    for (int i = es; i < cnt; i += 32) {
        const int i1 = i + 8, i2 = i + 16, i3 = i + 24;
        const bool b1v = i1 < cnt, b2v = i2 < cnt, b3v = i3 < cnt;
        int s0 = sorted_src[start + i];
        int s1 = sorted_src[start + (b1v ? i1 : i)];
        int s2 = sorted_src[start + (b2v ? i2 : i)];
        int s3 = sorted_src[start + (b3v ? i3 : i)];
        float a0 = a_s1[s0 * 8 + h];
        float a1 = a_s1[s1 * 8 + h];
        float a2 = a_s1[s2 * 8 + h];
        float a3 = a_s1[s3 * 8 + h];
        f16x8 v0 = *(const f16x8*)(h1 + (size_t)s0 * 64 + h * 8);
        f16x8 v1 = *(const f16x8*)(h1 + (size_t)s1 * 64 + h * 8);
        f16x8 v2 = *(const f16x8*)(h1 + (size_t)s2 * 64 + h * 8);
        f16x8 v3 = *(const f16x8*)(h1 + (size_t)s3 * 64 + h * 8);
        {
            float e = a0 + adn; e = e > 0.f ? e : 0.2f * e;
            if (e > m + 8.f) { float sc = __expf(m - e); denom *= sc;
                #pragma unroll
                for (int c = 0; c < 8; ++c) acc[c] *= sc; m = e; }
            float p = __expf(e - m); denom += p;
            #pragma unroll
            for (int c = 0; c < 8; ++c) acc[c] += p * (float)v0[c];
        }
        if (b1v) {
            float e = a1 + adn; e = e > 0.f ? e : 0.2f * e;
            if (e > m + 8.f) { float sc = __expf(m - e); denom *= sc;
                #pragma unroll
                for (int c = 0; c < 8; ++c) acc[c] *= sc; m = e; }
            float p = __expf(e - m); denom += p;
            #pragma unroll
            for (int c = 0; c < 8; ++c) acc[c] += p * (float)v1[c];
        }
        if (b2v) {
            float e = a2 + adn; e = e > 0.f ? e : 0.2f * e;
            if (e > m + 8.f) { float sc = __expf(m - e); denom *= sc;
                #pragma unroll
                for (int c = 0; c < 8; ++c) acc[c] *= sc; m = e; }
            float p = __expf(e - m); denom += p;
            #pragma unroll
            for (int c = 0; c < 8; ++c) acc[c] += p * (float)v2[c];
        }
        if (b3v) {
            float e = a3 + adn; e = e > 0.f ? e : 0.2f * e;
            if (e > m + 8.f) { float sc = __expf(m - e); denom *= sc;
                #pragma unroll
                for (int c = 0; c < 8; ++c) acc[c] *= sc; m = e; }
            float p = __expf(e - m); denom += p;
            #pragma unroll
            for (int c = 0; c < 8; ++c) acc[c] += p * (float)v3[c];
        }
    }
    // combine 8 edge-slots per head (xor 8,16,32); m may differ after rescales
    #pragma unroll
    for (int d = 8; d < 64; d <<= 1) {
        float mo = __shfl_xor(m, d);
        float dn = __shfl_xor(denom, d);
        float mn = fmaxf(m, mo);
        float sa = __expf(m - mn), sb = __expf(mo - mn);
        denom = denom * sa + dn * sb;
        #pragma unroll
        for (int c = 0; c < 8; ++c) {
            float ao = __shfl_xor(acc[c], d);
            acc[c] = acc[c] * sa + ao * sb;
        }
        m = mn;
    }
    float inv = 1.f / (denom + 1e-16f);
    float hc[8];
    #pragma unroll
    for (int c = 0; c < 8; ++c) {
        float v = acc[c] * inv;
        v += __shfl_xor(v, 1);
        v += __shfl_xor(v, 2);
        v += __shfl_xor(v, 4);                  // mean over heads
        float o = 0.125f * v + b1[c];
        hc[c] = o > 0.f ? o : expm1f(o);        // ELU
    }
    if (lane == 0) {
        float s2 = 0.f, d2 = 0.f;
        f16x8 gr;
        #pragma unroll
        for (int j = 0; j < 7; ++j) {
            float t = 0.f;
            #pragma unroll
            for (int c = 0; c < 8; ++c) t += hc[c] * w2[c * 7 + j];
            gr[j] = (_Float16)t;
            s2 += t * att_src2[j];
            d2 += t * att_dst2[j];
        }
        gr[7] = (_Float16)0.f;
        *(f16x8*)(g + (size_t)n * 8) = gr;
        a_s2[n] = s2;
        a_d2[n] = d2;
    }
}

// ---------------- layer-2 aggregate (defer-max, 4-deep batching) + log_softmax ----------------
__global__ __launch_bounds__(256) void k_agg2(
    const int* __restrict__ offsets, const int* __restrict__ counts,
    const int* __restrict__ sorted_src,
    const float* __restrict__ a_s2, const float* __restrict__ a_d2,
    const _Float16* __restrict__ g, const float* __restrict__ b2,
    float* __restrict__ outp) {
    const int tid  = threadIdx.x;
    const int lane = tid & 63;
    const int wave = tid >> 6;
    const int grp  = lane >> 3;
    const int s    = lane & 7;
    const int n    = blockIdx.x * 32 + wave * 8 + grp;
    const int start = offsets[n];
    const int cnt   = counts[n];
    const float adn = a_d2[n];
    float et = a_s2[n] + adn;
    const float e_self = et > 0.f ? et : 0.2f * et;

    float m = e_self, denom = 0.f;
    float acc[8] = {0.f,0.f,0.f,0.f,0.f,0.f,0.f,0.f};
    if (s == 0) {
        denom = 1.f;
        f16x8 gv0 = *(const f16x8*)(g + (size_t)n * 8);
        #pragma unroll
        for (int c = 0; c < 8; ++c) acc[c] = (float)gv0[c];
    }
    for (int i = s; i < cnt; i += 32) {
        const int i1 = i + 8, i2 = i + 16, i3 = i + 24;
        const bool b1v = i1 < cnt, b2v = i2 < cnt, b3v = i3 < cnt;
        int s0 = sorted_src[start + i];
        int s1 = sorted_src[start + (b1v ? i1 : i)];
        int s2 = sorted_src[start + (b2v ? i2 : i)];
        int s3 = sorted_src[start + (b3v ? i3 : i)];
        float a0 = a_s2[s0], a1 = a_s2[s1], a2 = a_s2[s2], a3 = a_s2[s3];
        f16x8 v0 = *(const f16x8*)(g + (size_t)s0 * 8);
        f16x8 v1 = *(const f16x8*)(g + (size_t)s1 * 8);
        f16x8 v2 = *(const f16x8*)(g + (size_t)s2 * 8);
        f16x8 v3 = *(const f16x8*)(g + (size_t)s3 * 8);
        {
            float e = a0 + adn; e = e > 0.f ? e : 0.2f * e;
            if (e > m + 8.f) { float sc = __expf(m - e); denom *= sc;
                #pragma unroll
                for (int c = 0; c < 8; ++c) acc[c] *= sc; m = e; }
            float p = __expf(e - m); denom += p;
            #pragma unroll
            for (int c = 0; c < 8; ++c) acc[c] += p * (float)v0[c];
        }
        if (b1v) {
            float e = a1 + adn; e = e > 0.f ? e : 0.2f * e;
            if (e > m + 8.f) { float sc = __expf(m - e); denom *= sc;
                #pragma unroll
                for (int c = 0; c < 8; ++c) acc[c] *= sc; m = e; }
            float p = __expf(e - m); denom += p;
            #pragma unroll
            for (int c = 0; c < 8; ++c) acc[c] += p * (float)v1[c];
        }
        if (b2v) {
            float e = a2 + adn; e = e > 0.f ? e : 0.2f * e;
            if (e > m + 8.f) { float sc = __expf(m - e); denom *= sc;
                #pragma unroll
                for (int c = 0; c < 8; ++c) acc[c] *= sc; m = e; }
            float p = __expf(e - m); denom += p;
            #pragma unroll
            for (int c = 0; c < 8; ++c) acc[c] += p * (float)v2[c];
        }
        if (b3v) {
            float e = a3 + adn; e = e > 0.f ? e : 0.2f * e;
            if (e > m + 8.f) { float sc = __expf(m - e); denom *= sc;
                #pragma unroll
                for (int c = 0; c < 8; ++c) acc[c] *= sc; m = e; }
            float p = __expf(e - m); denom += p;
            #pragma unroll
            for (int c = 0; c < 8; ++c) acc[c] += p * (float)v3[c];
        }
    }
    #pragma unroll
    for (int d = 1; d < 8; d <<= 1) {
        float mo = __shfl_xor(m, d, 8);
        float dn = __shfl_xor(denom, d, 8);
        float mn = fmaxf(m, mo);
        float sa = __expf(m - mn), sb = __expf(mo - mn);
        denom = denom * sa + dn * sb;
        #pragma unroll
        for (int c = 0; c < 8; ++c) {
            float ao = __shfl_xor(acc[c], d, 8);
            acc[c] = acc[c] * sa + ao * sb;
        }
        m = mn;
    }
    float inv = 1.f / (denom + 1e-16f);
    float o[7]; float mx = -1e30f;
    #pragma unroll
    for (int c = 0; c < 7; ++c) { o[c] = acc[c] * inv + b2[c]; mx = fmaxf(mx, o[c]); }
    float se = 0.f;
    #pragma unroll
    for (int c = 0; c < 7; ++c) se += __expf(o[c] - mx);
    float ls = mx + logf(se);
    if (s < 7) outp[n * 7 + s] = o[s] - ls;
}

extern "C" void kernel_launch(void* const* d_in, const int* in_sizes, int n_in,
                              void* d_out, int out_size, void* d_ws, size_t ws_size,
                              hipStream_t stream) {
    const float* x        = (const float*)d_in[0];
    const int*   ei       = (const int*)d_in[1];
    const float* W1       = (const float*)d_in[2];
    const float* att_src1 = (const float*)d_in[3];
    const float* att_dst1 = (const float*)d_in[4];
    const float* b1       = (const float*)d_in[5];
    const float* W2       = (const float*)d_in[6];
    const float* att_src2 = (const float*)d_in[7];
    const float* att_dst2 = (const float*)d_in[8];
    const float* b2       = (const float*)d_in[9];
    const int* src = ei;
    const int* dst = ei + E_EDGES;

    char* ws = (char*)d_ws;
    size_t off = 0;
    auto alloc = [&](size_t bytes) -> char* {
        char* p = ws + off;
        off = (off + bytes + 255) & ~(size_t)255;
        return p;
    };
    _Float16* h1         = (_Float16*)alloc((size_t)N_NODES * 64 * 2);
    float*    a_s1       = (float*)   alloc((size_t)N_NODES * 8 * 4);
    float*    a_d1       = (float*)   alloc((size_t)N_NODES * 8 * 4);
    _Float16* w1t        = (_Float16*)alloc((size_t)64 * K_PAD * 2);
    int*      counts     = (int*)     alloc((size_t)N_NODES * 4);
    int*      offsets    = (int*)     alloc((size_t)N_NODES * 4);
    int*      cursor     = (int*)     alloc((size_t)N_NODES * 4);
    int*      csum       = (int*)     alloc((size_t)NCH * 4);
    int*      sorted_src = (int*)     alloc((size_t)(E_EDGES + 32) * 4);
    _Float16* gbuf       = (_Float16*)alloc((size_t)N_NODES * 8 * 2);
    float*    a_s2       = (float*)   alloc((size_t)N_NODES * 4);
    float*    a_d2       = (float*)   alloc((size_t)N_NODES * 4);
    float*    outp       = (float*)d_out;

    hipLaunchKernelGGL(k_init,      dim3(391),   dim3(256), 0, stream, W1, w1t, counts);
    hipLaunchKernelGGL(k_hist,      dim3(3125),  dim3(256), 0, stream, dst, counts);
    hipLaunchKernelGGL(k_scan_a,    dim3(NCH),   dim3(256), 0, stream, counts, csum);
    hipLaunchKernelGGL(k_scan_b,    dim3(1),     dim3(128), 0, stream, csum);
    hipLaunchKernelGGL(k_scan_c,    dim3(NCH),   dim3(256), 0, stream, counts, csum, offsets, cursor);
    hipLaunchKernelGGL(k_gemm_scat, dim3(GEMM_BLOCKS + 3125), dim3(256), 0, stream,
                       x, w1t, att_src1, att_dst1, h1, a_s1, a_d1,
                       src, dst, cursor, sorted_src);
    hipLaunchKernelGGL(k_agg1,      dim3(25000), dim3(256), 0, stream, offsets, counts, sorted_src,
                       a_s1, a_d1, h1, b1, W2, att_src2, att_dst2, gbuf, a_s2, a_d2);
    hipLaunchKernelGGL(k_agg2,      dim3(3125),  dim3(256), 0, stream, offsets, counts, sorted_src,
                       a_s2, a_d2, gbuf, b2, outp);
}

// Round 13
// 541.832 us; speedup vs baseline: 1.4326x; 1.0501x over previous
//
#include <hip/hip_runtime.h>

#define N_NODES 100000
#define E_EDGES 3200000
#define F_IN    1433
#define K_PAD   1472   // w1t padded K (23*64)
#define NCH     98     // scan chunks of 1024
#define KPH     64     // k per phase; 22 DMA phases + guarded tail

typedef _Float16 f16x4 __attribute__((ext_vector_type(4)));
typedef _Float16 f16x8 __attribute__((ext_vector_type(8)));
typedef float    f32x4 __attribute__((ext_vector_type(4)));

__device__ __forceinline__ void gload_lds16(const void* g, void* l) {
    __builtin_amdgcn_global_load_lds(
        (const __attribute__((address_space(1))) unsigned int*)g,
        (__attribute__((address_space(3))) unsigned int*)l, 16, 0, 0);
}

// ---------------- init: counts=0 + W1^T fp16 [64][K_PAD] zero-padded ----------------
__global__ void k_init(const float* __restrict__ w1, _Float16* __restrict__ w1t,
                       int* __restrict__ counts) {
    int i = blockIdx.x * 256 + threadIdx.x;
    if (i < N_NODES) counts[i] = 0;
    if (i < 64 * K_PAD) {
        int n = i / K_PAD, k = i - n * K_PAD;
        float v = (k < F_IN) ? w1[(size_t)k * 64 + n] : 0.f;
        w1t[i] = (_Float16)v;
    }
}

__global__ void k_hist(const int* __restrict__ dst, int* __restrict__ counts) {
    int idx = blockIdx.x * 256 + threadIdx.x;      // 3125*256*4 = 3.2M
    int4 d4 = ((const int4*)dst)[idx];
    atomicAdd(&counts[d4.x], 1);
    atomicAdd(&counts[d4.y], 1);
    atomicAdd(&counts[d4.z], 1);
    atomicAdd(&counts[d4.w], 1);
}

// ---------------- exclusive scan of counts (chunked) ----------------
__global__ void k_scan_a(const int* __restrict__ counts, int* __restrict__ csum) {
    __shared__ int sh[256];
    int b = blockIdx.x, t = threadIdx.x;
    int s = 0;
    for (int j = 0; j < 4; ++j) {
        int idx = b * 1024 + j * 256 + t;
        if (idx < N_NODES) s += counts[idx];
    }
    sh[t] = s; __syncthreads();
    for (int off = 128; off > 0; off >>= 1) {
        if (t < off) sh[t] += sh[t + off];
        __syncthreads();
    }
    if (t == 0) csum[b] = sh[0];
}

__global__ void k_scan_b(int* __restrict__ csum) {
    __shared__ int sh[128];
    int t = threadIdx.x;
    int v = (t < NCH) ? csum[t] : 0;
    sh[t] = v; __syncthreads();
    for (int off = 1; off < 128; off <<= 1) {
        int u = (t >= off) ? sh[t - off] : 0;
        __syncthreads();
        sh[t] += u;
        __syncthreads();
    }
    if (t < NCH) csum[t] = sh[t] - v;   // exclusive
}

__global__ void k_scan_c(const int* __restrict__ counts, const int* __restrict__ csum,
                         int* __restrict__ offsets, int* __restrict__ cursor) {
    __shared__ int sh[256];
    int b = blockIdx.x, t = threadIdx.x;
    int base = b * 1024 + t * 4;
    int c0 = (base + 0 < N_NODES) ? counts[base + 0] : 0;
    int c1 = (base + 1 < N_NODES) ? counts[base + 1] : 0;
    int c2 = (base + 2 < N_NODES) ? counts[base + 2] : 0;
    int c3 = (base + 3 < N_NODES) ? counts[base + 3] : 0;
    int tot = c0 + c1 + c2 + c3;
    sh[t] = tot; __syncthreads();
    for (int off = 1; off < 256; off <<= 1) {
        int v = (t >= off) ? sh[t - off] : 0;
        __syncthreads();
        sh[t] += v;
        __syncthreads();
    }
    int excl = sh[t] - tot;
    int o = csum[b] + excl;
    if (base + 0 < N_NODES) { offsets[base + 0] = o;            cursor[base + 0] = o; }
    if (base + 1 < N_NODES) { int q = o + c0;      offsets[base + 1] = q; cursor[base + 1] = q; }
    if (base + 2 < N_NODES) { int q = o + c0 + c1; offsets[base + 2] = q; cursor[base + 2] = q; }
    if (base + 3 < N_NODES) { int q = o + c0 + c1 + c2; offsets[base + 3] = q; cursor[base + 3] = q; }
}

// ---------------- FUSED: even blocks = gemm1(+att1), odd blocks = scatter ----------------
// Roles ALTERNATE so each CU's 3 resident slots hold a mix: scatter's memory ops
// fill gemm's stall cycles. gemm uses a 2-deep counted-vmcnt DMA pipeline:
// wait vmcnt(6) (current buffer's 6 DMAs done, next phase's 6 stay in flight),
// never a full drain in the steady-state loop.
__global__ __launch_bounds__(256) void k_gemm_scat(const float* __restrict__ x,
                                                   const _Float16* __restrict__ w1t,
                                                   const float* __restrict__ att_src1,
                                                   const float* __restrict__ att_dst1,
                                                   _Float16* __restrict__ h1,
                                                   float* __restrict__ a_s1,
                                                   float* __restrict__ a_d1,
                                                   const int* __restrict__ src,
                                                   const int* __restrict__ dst,
                                                   int* __restrict__ cursor,
                                                   int* __restrict__ sorted_src) {
    __shared__ __align__(16) char AsB[2][64 * 256];   // 16 KB per buffer (fp32)
    __shared__ __align__(16) char BsB[2][64 * 128];   //  8 KB per buffer (fp16)
    const int tid = threadIdx.x;

    if (blockIdx.x & 1) {
        // ---------------- scatter role: 2048 edges per block ----------------
        const int sid = blockIdx.x >> 1;
        #pragma unroll
        for (int rep = 0; rep < 2; ++rep) {
            int i4 = sid * 512 + rep * 256 + tid;
            if (i4 < E_EDGES / 4) {
                int4 s4 = ((const int4*)src)[i4];
                int4 d4 = ((const int4*)dst)[i4];
                int p;
                p = atomicAdd(&cursor[d4.x], 1); sorted_src[p] = s4.x;
                p = atomicAdd(&cursor[d4.y], 1); sorted_src[p] = s4.y;
                p = atomicAdd(&cursor[d4.z], 1); sorted_src[p] = s4.z;
                p = atomicAdd(&cursor[d4.w], 1); sorted_src[p] = s4.w;
            }
        }
        return;
    }

    // ---------------- gemm1 role ----------------
    const int gid  = blockIdx.x >> 1;
    const int lane = tid & 63;
    const int wave = tid >> 6;
    const int l16  = lane & 15;
    const int l4   = lane >> 4;
    const int brow0 = gid * 64;

    f32x4 acc[4] = {};

    auto stageA = [&](int buf, int ph) {
        #pragma unroll
        for (int j = 0; j < 4; ++j) {
            int p = j * 256 + tid;
            int row = p >> 4, q = p & 15;
            int qs = q ^ (row & 7);
            int grow = brow0 + row; if (grow > N_NODES - 1) grow = N_NODES - 1;
            const float* gp = x + (size_t)grow * F_IN + ph * KPH + qs * 4;
            gload_lds16(gp, AsB[buf] + j * 4096 + wave * 1024);
        }
    };
    auto stageB = [&](int buf, int ph) {
        #pragma unroll
        for (int j = 0; j < 2; ++j) {
            int p = j * 256 + tid;
            int col = p >> 3, c = p & 7;
            int cs = c ^ (col & 7);
            const _Float16* gp = w1t + (size_t)col * K_PAD + ph * KPH + cs * 8;
            gload_lds16(gp, BsB[buf] + j * 4096 + wave * 1024);
        }
    };
    auto stageTailA = [&](int buf) {        // k 1408..1471, zero-fill k>=1433
        for (int i = tid; i < 1024; i += 256) {
            int row = i >> 4, q = i & 15;
            int qs = q ^ (row & 7);
            int grow = brow0 + row; if (grow > N_NODES - 1) grow = N_NODES - 1;
            const float* gp = x + (size_t)grow * F_IN;
            float4 v;
            #pragma unroll
            for (int jj = 0; jj < 4; ++jj) {
                int k = 1408 + qs * 4 + jj;
                ((float*)&v)[jj] = (k < F_IN) ? gp[k] : 0.f;
            }
            *(float4*)(AsB[buf] + row * 256 + q * 16) = v;
        }
    };
    auto compute = [&](int buf) {
        const int rA = wave * 16 + l16;
        const char* Ab = AsB[buf] + rA * 256;
        const int r7 = rA & 7;
        #pragma unroll
        for (int st = 0; st < 4; ++st) {
            float4 af = *(const float4*)(Ab + ((((st << 2) + l4) ^ r7) << 4));
            f16x4 a = { (_Float16)af.x, (_Float16)af.y, (_Float16)af.z, (_Float16)af.w };
            #pragma unroll
            for (int t = 0; t < 4; ++t) {
                const int cB = t * 16 + l16;
                const int chunk = (st << 1) + (l4 >> 1);
                const int boff = cB * 128 + ((chunk ^ (cB & 7)) << 4) + ((l4 & 1) << 3);
                f16x4 b = *(const f16x4*)(BsB[buf] + boff);
                acc[t] = __builtin_amdgcn_mfma_f32_16x16x16f16(a, b, acc[t], 0, 0, 0);
            }
        }
    };

    // prologue: stage phases 0 and 1 (12 DMAs in flight per wave)
    stageA(0, 0); stageB(0, 0);
    stageA(1, 1); stageB(1, 1);
    // steady state: compute(ph) from buf[ph&1]; stage(ph+2) into the freed buffer
    for (int ph = 0; ph <= 20; ++ph) {
        asm volatile("s_waitcnt vmcnt(6)" ::: "memory");   // buf[ph&1]'s 6 DMAs done
        __builtin_amdgcn_sched_barrier(0);
        __builtin_amdgcn_s_barrier();                      // all waves agree
        compute(ph & 1);
        asm volatile("s_waitcnt lgkmcnt(0)" ::: "memory"); // reads retired before overwrite
        __builtin_amdgcn_s_barrier();
        int nxt = ph + 2;
        if (nxt < 22)       { stageA(ph & 1, nxt); stageB(ph & 1, nxt); }
        else if (nxt == 22) { stageTailA(ph & 1);  stageB(ph & 1, 22);  }
    }
    // phases 21, 22: single drain
    asm volatile("s_waitcnt vmcnt(0) lgkmcnt(0)" ::: "memory");
    __builtin_amdgcn_sched_barrier(0);
    __builtin_amdgcn_s_barrier();
    compute(1);                            // phase 21 (buf1)
    compute(0);                            // phase 22 (buf0, tail)

    // epilogue: h1 write + fused attention coefficients (reduce over 8 channels)
    const int wrow0 = brow0 + wave * 16;
    #pragma unroll
    for (int t = 0; t < 4; ++t) {
        const int head = t * 2 + (l16 >> 3);
        const int ch   = l16 & 7;
        const float asc = att_src1[head * 8 + ch];
        const float adc = att_dst1[head * 8 + ch];
        #pragma unroll
        for (int j = 0; j < 4; ++j) {
            int r = wrow0 + l4 * 4 + j;    // C: col = lane&15, row = (lane>>4)*4 + reg
            float ps = acc[t][j] * asc, pd = acc[t][j] * adc;
            ps += __shfl_xor(ps, 1); ps += __shfl_xor(ps, 2); ps += __shfl_xor(ps, 4);
            pd += __shfl_xor(pd, 1); pd += __shfl_xor(pd, 2); pd += __shfl_xor(pd, 4);
            if (r < N_NODES) {
                h1[(size_t)r * 64 + t * 16 + l16] = (_Float16)acc[t][j];
                if (ch == 0) {
                    a_s1[r * 8 + head] = ps;
                    a_d1[r * 8 + head] = pd;
                }
            }
        }
    }
}

// ---------------- layer-1 aggregate (defer-max, 4-deep gather batching) ----------------
__global__ __launch_bounds__(256) void k_agg1(
    const int* __restrict__ offsets, const int* __restrict__ counts,
    const int* __restrict__ sorted_src,
    const float* __restrict__ a_s1, const float* __restrict__ a_d1,
    const _Float16* __restrict__ h1, const float* __restrict__ b1,
    const float* __restrict__ w2, const float* __restrict__ att_src2,
    const float* __restrict__ att_dst2,
    _Float16* __restrict__ g, float* __restrict__ a_s2, float* __restrict__ a_d2) {
    const int lane = threadIdx.x & 63;
    const int wave = threadIdx.x >> 6;
    const int h    = lane & 7;
    const int es   = lane >> 3;
    const int n    = blockIdx.x * 4 + wave;     // 25000*4 = 100000 exact
    const int start = offsets[n];
    const int cnt   = counts[n];
    const float adn = a_d1[n * 8 + h];
    float et = a_s1[n * 8 + h] + adn;
    const float e_self = et > 0.f ? et : 0.2f * et;

    float m = e_self, denom = 0.f;
    float acc[8] = {0.f,0.f,0.f,0.f,0.f,0.f,0.f,0.f};
    if (es == 0) {                 // self-loop: exp(e_self - m) = 1
        denom = 1.f;
        f16x8 hv0 = *(const f16x8*)(h1 + (size_t)n * 64 + h * 8);
        #pragma unroll
        for (int c = 0; c < 8; ++c) acc[c] = (float)hv0[c];
    }
    for (int i = es; i < cnt; i += 32) {
        const int i1 = i + 8, i2 = i + 16, i3 = i + 24;
        const bool b1v = i1 < cnt, b2v = i2 < cnt, b3v = i3 < cnt;
        int s0 = sorted_src[start + i];
        int s1 = sorted_src[start + (b1v ? i1 : i)];
        int s2 = sorted_src[start + (b2v ? i2 : i)];
        int s3 = sorted_src[start + (b3v ? i3 : i)];
        float a0 = a_s1[s0 * 8 + h];
        float a1 = a_s1[s1 * 8 + h];
        float a2 = a_s1[s2 * 8 + h];
        float a3 = a_s1[s3 * 8 + h];
        f16x8 v0 = *(const f16x8*)(h1 + (size_t)s0 * 64 + h * 8);
        f16x8 v1 = *(const f16x8*)(h1 + (size_t)s1 * 64 + h * 8);
        f16x8 v2 = *(const f16x8*)(h1 + (size_t)s2 * 64 + h * 8);
        f16x8 v3 = *(const f16x8*)(h1 + (size_t)s3 * 64 + h * 8);
        {
            float e = a0 + adn; e = e > 0.f ? e : 0.2f * e;
            if (e > m + 8.f) { float sc = __expf(m - e); denom *= sc;
                #pragma unroll
                for (int c = 0; c < 8; ++c) acc[c] *= sc; m = e; }
            float p = __expf(e - m); denom += p;
            #pragma unroll
            for (int c = 0; c < 8; ++c) acc[c] += p * (float)v0[c];
        }
        if (b1v) {
            float e = a1 + adn; e = e > 0.f ? e : 0.2f * e;
            if (e > m + 8.f) { float sc = __expf(m - e); denom *= sc;
                #pragma unroll
                for (int c = 0; c < 8; ++c) acc[c] *= sc; m = e; }
            float p = __expf(e - m); denom += p;
            #pragma unroll
            for (int c = 0; c < 8; ++c) acc[c] += p * (float)v1[c];
        }
        if (b2v) {
            float e = a2 + adn; e = e > 0.f ? e : 0.2f * e;
            if (e > m + 8.f) { float sc = __expf(m - e); denom *= sc;
                #pragma unroll
                for (int c = 0; c < 8; ++c) acc[c] *= sc; m = e; }
            float p = __expf(e - m); denom += p;
            #pragma unroll
            for (int c = 0; c < 8; ++c) acc[c] += p * (float)v2[c];
        }
        if (b3v) {
            float e = a3 + adn; e = e > 0.f ? e : 0.2f * e;
            if (e > m + 8.f) { float sc = __expf(m - e); denom *= sc;
                #pragma unroll
                for (int c = 0; c < 8; ++c) acc[c] *= sc; m = e; }
            float p = __expf(e - m); denom += p;
            #pragma unroll
            for (int c = 0; c < 8; ++c) acc[c] += p * (float)v3[c];
        }
    }
    // combine 8 edge-slots per head (xor 8,16,32); m may differ after rescales
    #pragma unroll
    for (int d = 8; d < 64; d <<= 1) {
        float mo = __shfl_xor(m, d);
        float dn = __shfl_xor(denom, d);
        float mn = fmaxf(m, mo);
        float sa = __expf(m - mn), sb = __expf(mo - mn);
        denom = denom * sa + dn * sb;
        #pragma unroll
        for (int c = 0; c < 8; ++c) {
            float ao = __shfl_xor(acc[c], d);
            acc[c] = acc[c] * sa + ao * sb;
        }
        m = mn;
    }
    float inv = 1.f / (denom + 1e-16f);
    float hc[8];
    #pragma unroll
    for (int c = 0; c < 8; ++c) {
        float v = acc[c] * inv;
        v += __shfl_xor(v, 1);
        v += __shfl_xor(v, 2);
        v += __shfl_xor(v, 4);                  // mean over heads
        float o = 0.125f * v + b1[c];
        hc[c] = o > 0.f ? o : expm1f(o);        // ELU
    }
    if (lane == 0) {
        float s2 = 0.f, d2 = 0.f;
        f16x8 gr;
        #pragma unroll
        for (int j = 0; j < 7; ++j) {
            float t = 0.f;
            #pragma unroll
            for (int c = 0; c < 8; ++c) t += hc[c] * w2[c * 7 + j];
            gr[j] = (_Float16)t;
            s2 += t * att_src2[j];
            d2 += t * att_dst2[j];
        }
        gr[7] = (_Float16)0.f;
        *(f16x8*)(g + (size_t)n * 8) = gr;
        a_s2[n] = s2;
        a_d2[n] = d2;
    }
}

// ---------------- layer-2 aggregate (defer-max, 4-deep batching) + log_softmax ----------------
__global__ __launch_bounds__(256) void k_agg2(
    const int* __restrict__ offsets, const int* __restrict__ counts,
    const int* __restrict__ sorted_src,
    const float* __restrict__ a_s2, const float* __restrict__ a_d2,
    const _Float16* __restrict__ g, const float* __restrict__ b2,
    float* __restrict__ outp) {
    const int tid  = threadIdx.x;
    const int lane = tid & 63;
    const int wave = tid >> 6;
    const int grp  = lane >> 3;
    const int s    = lane & 7;
    const int n    = blockIdx.x * 32 + wave * 8 + grp;
    const int start = offsets[n];
    const int cnt   = counts[n];
    const float adn = a_d2[n];
    float et = a_s2[n] + adn;
    const float e_self = et > 0.f ? et : 0.2f * et;

    float m = e_self, denom = 0.f;
    float acc[8] = {0.f,0.f,0.f,0.f,0.f,0.f,0.f,0.f};
    if (s == 0) {
        denom = 1.f;
        f16x8 gv0 = *(const f16x8*)(g + (size_t)n * 8);
        #pragma unroll
        for (int c = 0; c < 8; ++c) acc[c] = (float)gv0[c];
    }
    for (int i = s; i < cnt; i += 32) {
        const int i1 = i + 8, i2 = i + 16, i3 = i + 24;
        const bool b1v = i1 < cnt, b2v = i2 < cnt, b3v = i3 < cnt;
        int s0 = sorted_src[start + i];
        int s1 = sorted_src[start + (b1v ? i1 : i)];
        int s2 = sorted_src[start + (b2v ? i2 : i)];
        int s3 = sorted_src[start + (b3v ? i3 : i)];
        float a0 = a_s2[s0], a1 = a_s2[s1], a2 = a_s2[s2], a3 = a_s2[s3];
        f16x8 v0 = *(const f16x8*)(g + (size_t)s0 * 8);
        f16x8 v1 = *(const f16x8*)(g + (size_t)s1 * 8);
        f16x8 v2 = *(const f16x8*)(g + (size_t)s2 * 8);
        f16x8 v3 = *(const f16x8*)(g + (size_t)s3 * 8);
        {
            float e = a0 + adn; e = e > 0.f ? e : 0.2f * e;
            if (e > m + 8.f) { float sc = __expf(m - e); denom *= sc;
                #pragma unroll
                for (int c = 0; c < 8; ++c) acc[c] *= sc; m = e; }
            float p = __expf(e - m); denom += p;
            #pragma unroll
            for (int c = 0; c < 8; ++c) acc[c] += p * (float)v0[c];
        }
        if (b1v) {
            float e = a1 + adn; e = e > 0.f ? e : 0.2f * e;
            if (e > m + 8.f) { float sc = __expf(m - e); denom *= sc;
                #pragma unroll
                for (int c = 0; c < 8; ++c) acc[c] *= sc; m = e; }
            float p = __expf(e - m); denom += p;
            #pragma unroll
            for (int c = 0; c < 8; ++c) acc[c] += p * (float)v1[c];
        }
        if (b2v) {
            float e = a2 + adn; e = e > 0.f ? e : 0.2f * e;
            if (e > m + 8.f) { float sc = __expf(m - e); denom *= sc;
                #pragma unroll
                for (int c = 0; c < 8; ++c) acc[c] *= sc; m = e; }
            float p = __expf(e - m); denom += p;
            #pragma unroll
            for (int c = 0; c < 8; ++c) acc[c] += p * (float)v2[c];
        }
        if (b3v) {
            float e = a3 + adn; e = e > 0.f ? e : 0.2f * e;
            if (e > m + 8.f) { float sc = __expf(m - e); denom *= sc;
                #pragma unroll
                for (int c = 0; c < 8; ++c) acc[c] *= sc; m = e; }
            float p = __expf(e - m); denom += p;
            #pragma unroll
            for (int c = 0; c < 8; ++c) acc[c] += p * (float)v3[c];
        }
    }
    #pragma unroll
    for (int d = 1; d < 8; d <<= 1) {
        float mo = __shfl_xor(m, d, 8);
        float dn = __shfl_xor(denom, d, 8);
        float mn = fmaxf(m, mo);
        float sa = __expf(m - mn), sb = __expf(mo - mn);
        denom = denom * sa + dn * sb;
        #pragma unroll
        for (int c = 0; c < 8; ++c) {
            float ao = __shfl_xor(acc[c], d, 8);
            acc[c] = acc[c] * sa + ao * sb;
        }
        m = mn;
    }
    float inv = 1.f / (denom + 1e-16f);
    float o[7]; float mx = -1e30f;
    #pragma unroll
    for (int c = 0; c < 7; ++c) { o[c] = acc[c] * inv + b2[c]; mx = fmaxf(mx, o[c]); }
    float se = 0.f;
    #pragma unroll
    for (int c = 0; c < 7; ++c) se += __expf(o[c] - mx);
    float ls = mx + logf(se);
    if (s < 7) outp[n * 7 + s] = o[s] - ls;
}

extern "C" void kernel_launch(void* const* d_in, const int* in_sizes, int n_in,
                              void* d_out, int out_size, void* d_ws, size_t ws_size,
                              hipStream_t stream) {
    const float* x        = (const float*)d_in[0];
    const int*   ei       = (const int*)d_in[1];
    const float* W1       = (const float*)d_in[2];
    const float* att_src1 = (const float*)d_in[3];
    const float* att_dst1 = (const float*)d_in[4];
    const float* b1       = (const float*)d_in[5];
    const float* W2       = (const float*)d_in[6];
    const float* att_src2 = (const float*)d_in[7];
    const float* att_dst2 = (const float*)d_in[8];
    const float* b2       = (const float*)d_in[9];
    const int* src = ei;
    const int* dst = ei + E_EDGES;

    char* ws = (char*)d_ws;
    size_t off = 0;
    auto alloc = [&](size_t bytes) -> char* {
        char* p = ws + off;
        off = (off + bytes + 255) & ~(size_t)255;
        return p;
    };
    _Float16* h1         = (_Float16*)alloc((size_t)N_NODES * 64 * 2);
    float*    a_s1       = (float*)   alloc((size_t)N_NODES * 8 * 4);
    float*    a_d1       = (float*)   alloc((size_t)N_NODES * 8 * 4);
    _Float16* w1t        = (_Float16*)alloc((size_t)64 * K_PAD * 2);
    int*      counts     = (int*)     alloc((size_t)N_NODES * 4);
    int*      offsets    = (int*)     alloc((size_t)N_NODES * 4);
    int*      cursor     = (int*)     alloc((size_t)N_NODES * 4);
    int*      csum       = (int*)     alloc((size_t)NCH * 4);
    int*      sorted_src = (int*)     alloc((size_t)(E_EDGES + 32) * 4);
    _Float16* gbuf       = (_Float16*)alloc((size_t)N_NODES * 8 * 2);
    float*    a_s2       = (float*)   alloc((size_t)N_NODES * 4);
    float*    a_d2       = (float*)   alloc((size_t)N_NODES * 4);
    float*    outp       = (float*)d_out;

    hipLaunchKernelGGL(k_init,      dim3(391),   dim3(256), 0, stream, W1, w1t, counts);
    hipLaunchKernelGGL(k_hist,      dim3(3125),  dim3(256), 0, stream, dst, counts);
    hipLaunchKernelGGL(k_scan_a,    dim3(NCH),   dim3(256), 0, stream, counts, csum);
    hipLaunchKernelGGL(k_scan_b,    dim3(1),     dim3(128), 0, stream, csum);
    hipLaunchKernelGGL(k_scan_c,    dim3(NCH),   dim3(256), 0, stream, counts, csum, offsets, cursor);
    hipLaunchKernelGGL(k_gemm_scat, dim3(3126),  dim3(256), 0, stream,
                       x, w1t, att_src1, att_dst1, h1, a_s1, a_d1,
                       src, dst, cursor, sorted_src);
    hipLaunchKernelGGL(k_agg1,      dim3(25000), dim3(256), 0, stream, offsets, counts, sorted_src,
                       a_s1, a_d1, h1, b1, W2, att_src2, att_dst2, gbuf, a_s2, a_d2);
    hipLaunchKernelGGL(k_agg2,      dim3(3125),  dim3(256), 0, stream, offsets, counts, sorted_src,
                       a_s2, a_d2, gbuf, b2, outp);
}

// Round 14
// 535.064 us; speedup vs baseline: 1.4508x; 1.0126x over previous
//
#include <hip/hip_runtime.h>

#define N_NODES 100000
#define E_EDGES 3200000
#define F_IN    1433
#define K_PAD   1472   // w1t padded K (23*64)
#define NCH     98     // scan chunks of 1024
#define KPH     64     // k per phase; 22 DMA phases + guarded tail

typedef _Float16 f16x4 __attribute__((ext_vector_type(4)));
typedef _Float16 f16x8 __attribute__((ext_vector_type(8)));
typedef float    f32x4 __attribute__((ext_vector_type(4)));

__device__ __forceinline__ void gload_lds16(const void* g, void* l) {
    __builtin_amdgcn_global_load_lds(
        (const __attribute__((address_space(1))) unsigned int*)g,
        (__attribute__((address_space(3))) unsigned int*)l, 16, 0, 0);
}

// ---------------- init: counts=0 + W1^T fp16 [64][K_PAD] zero-padded ----------------
__global__ void k_init(const float* __restrict__ w1, _Float16* __restrict__ w1t,
                       int* __restrict__ counts) {
    int i = blockIdx.x * 256 + threadIdx.x;
    if (i < N_NODES) counts[i] = 0;
    if (i < 64 * K_PAD) {
        int n = i / K_PAD, k = i - n * K_PAD;
        float v = (k < F_IN) ? w1[(size_t)k * 64 + n] : 0.f;
        w1t[i] = (_Float16)v;
    }
}

__global__ void k_hist(const int* __restrict__ dst, int* __restrict__ counts) {
    int idx = blockIdx.x * 256 + threadIdx.x;      // 3125*256*4 = 3.2M
    int4 d4 = ((const int4*)dst)[idx];
    atomicAdd(&counts[d4.x], 1);
    atomicAdd(&counts[d4.y], 1);
    atomicAdd(&counts[d4.z], 1);
    atomicAdd(&counts[d4.w], 1);
}

// ---------------- exclusive scan of counts (chunked) ----------------
__global__ void k_scan_a(const int* __restrict__ counts, int* __restrict__ csum) {
    __shared__ int sh[256];
    int b = blockIdx.x, t = threadIdx.x;
    int s = 0;
    for (int j = 0; j < 4; ++j) {
        int idx = b * 1024 + j * 256 + t;
        if (idx < N_NODES) s += counts[idx];
    }
    sh[t] = s; __syncthreads();
    for (int off = 128; off > 0; off >>= 1) {
        if (t < off) sh[t] += sh[t + off];
        __syncthreads();
    }
    if (t == 0) csum[b] = sh[0];
}

__global__ void k_scan_b(int* __restrict__ csum) {
    __shared__ int sh[128];
    int t = threadIdx.x;
    int v = (t < NCH) ? csum[t] : 0;
    sh[t] = v; __syncthreads();
    for (int off = 1; off < 128; off <<= 1) {
        int u = (t >= off) ? sh[t - off] : 0;
        __syncthreads();
        sh[t] += u;
        __syncthreads();
    }
    if (t < NCH) csum[t] = sh[t] - v;   // exclusive
}

__global__ void k_scan_c(const int* __restrict__ counts, const int* __restrict__ csum,
                         int* __restrict__ offsets, int* __restrict__ cursor) {
    __shared__ int sh[256];
    int b = blockIdx.x, t = threadIdx.x;
    int base = b * 1024 + t * 4;
    int c0 = (base + 0 < N_NODES) ? counts[base + 0] : 0;
    int c1 = (base + 1 < N_NODES) ? counts[base + 1] : 0;
    int c2 = (base + 2 < N_NODES) ? counts[base + 2] : 0;
    int c3 = (base + 3 < N_NODES) ? counts[base + 3] : 0;
    int tot = c0 + c1 + c2 + c3;
    sh[t] = tot; __syncthreads();
    for (int off = 1; off < 256; off <<= 1) {
        int v = (t >= off) ? sh[t - off] : 0;
        __syncthreads();
        sh[t] += v;
        __syncthreads();
    }
    int excl = sh[t] - tot;
    int o = csum[b] + excl;
    if (base + 0 < N_NODES) { offsets[base + 0] = o;            cursor[base + 0] = o; }
    if (base + 1 < N_NODES) { int q = o + c0;      offsets[base + 1] = q; cursor[base + 1] = q; }
    if (base + 2 < N_NODES) { int q = o + c0 + c1; offsets[base + 2] = q; cursor[base + 2] = q; }
    if (base + 3 < N_NODES) { int q = o + c0 + c1 + c2; offsets[base + 3] = q; cursor[base + 3] = q; }
}

// ---------------- FUSED: even blocks = gemm1(+att1), odd blocks = scatter ----------------
// Scatter role is SWEEP-LOCALIZED: 7 sweeps over the block's (L1-resident) edge
// chunk, sweep s handling only dst>>14 == s. Concurrent sorted_src writes then
// target a ~1.8 MB L2-resident window -> lines fill before eviction, killing the
// 7x write amplification measured in r12 (WRITE_SIZE 222 MB vs 32 MB useful).
// Per-dst CSR order is unchanged (all edges of a dst share a sweep).
__global__ __launch_bounds__(256) void k_gemm_scat(const float* __restrict__ x,
                                                   const _Float16* __restrict__ w1t,
                                                   const float* __restrict__ att_src1,
                                                   const float* __restrict__ att_dst1,
                                                   _Float16* __restrict__ h1,
                                                   float* __restrict__ a_s1,
                                                   float* __restrict__ a_d1,
                                                   const int* __restrict__ src,
                                                   const int* __restrict__ dst,
                                                   int* __restrict__ cursor,
                                                   int* __restrict__ sorted_src) {
    __shared__ __align__(16) char AsB[2][64 * 256];   // 16 KB per buffer (fp32)
    __shared__ __align__(16) char BsB[2][64 * 128];   //  8 KB per buffer (fp16)
    const int tid = threadIdx.x;

    if (blockIdx.x & 1) {
        // ---------------- scatter role: 2048 edges per block, 7 dst-range sweeps ----------------
        const int sid = blockIdx.x >> 1;
        for (int sweep = 0; sweep < 7; ++sweep) {     // dst>>14: 0..6 for dst<100000
            #pragma unroll
            for (int rep = 0; rep < 2; ++rep) {
                int i4 = sid * 512 + rep * 256 + tid;
                if (i4 < E_EDGES / 4) {
                    int4 s4 = ((const int4*)src)[i4];
                    int4 d4 = ((const int4*)dst)[i4];
                    int p;
                    if ((d4.x >> 14) == sweep) { p = atomicAdd(&cursor[d4.x], 1); sorted_src[p] = s4.x; }
                    if ((d4.y >> 14) == sweep) { p = atomicAdd(&cursor[d4.y], 1); sorted_src[p] = s4.y; }
                    if ((d4.z >> 14) == sweep) { p = atomicAdd(&cursor[d4.z], 1); sorted_src[p] = s4.z; }
                    if ((d4.w >> 14) == sweep) { p = atomicAdd(&cursor[d4.w], 1); sorted_src[p] = s4.w; }
                }
            }
        }
        return;
    }

    // ---------------- gemm1 role (unchanged from r13, verified) ----------------
    const int gid  = blockIdx.x >> 1;
    const int lane = tid & 63;
    const int wave = tid >> 6;
    const int l16  = lane & 15;
    const int l4   = lane >> 4;
    const int brow0 = gid * 64;

    f32x4 acc[4] = {};

    auto stageA = [&](int buf, int ph) {
        #pragma unroll
        for (int j = 0; j < 4; ++j) {
            int p = j * 256 + tid;
            int row = p >> 4, q = p & 15;
            int qs = q ^ (row & 7);
            int grow = brow0 + row; if (grow > N_NODES - 1) grow = N_NODES - 1;
            const float* gp = x + (size_t)grow * F_IN + ph * KPH + qs * 4;
            gload_lds16(gp, AsB[buf] + j * 4096 + wave * 1024);
        }
    };
    auto stageB = [&](int buf, int ph) {
        #pragma unroll
        for (int j = 0; j < 2; ++j) {
            int p = j * 256 + tid;
            int col = p >> 3, c = p & 7;
            int cs = c ^ (col & 7);
            const _Float16* gp = w1t + (size_t)col * K_PAD + ph * KPH + cs * 8;
            gload_lds16(gp, BsB[buf] + j * 4096 + wave * 1024);
        }
    };
    auto stageTailA = [&](int buf) {        // k 1408..1471, zero-fill k>=1433
        for (int i = tid; i < 1024; i += 256) {
            int row = i >> 4, q = i & 15;
            int qs = q ^ (row & 7);
            int grow = brow0 + row; if (grow > N_NODES - 1) grow = N_NODES - 1;
            const float* gp = x + (size_t)grow * F_IN;
            float4 v;
            #pragma unroll
            for (int jj = 0; jj < 4; ++jj) {
                int k = 1408 + qs * 4 + jj;
                ((float*)&v)[jj] = (k < F_IN) ? gp[k] : 0.f;
            }
            *(float4*)(AsB[buf] + row * 256 + q * 16) = v;
        }
    };
    auto compute = [&](int buf) {
        const int rA = wave * 16 + l16;
        const char* Ab = AsB[buf] + rA * 256;
        const int r7 = rA & 7;
        #pragma unroll
        for (int st = 0; st < 4; ++st) {
            float4 af = *(const float4*)(Ab + ((((st << 2) + l4) ^ r7) << 4));
            f16x4 a = { (_Float16)af.x, (_Float16)af.y, (_Float16)af.z, (_Float16)af.w };
            #pragma unroll
            for (int t = 0; t < 4; ++t) {
                const int cB = t * 16 + l16;
                const int chunk = (st << 1) + (l4 >> 1);
                const int boff = cB * 128 + ((chunk ^ (cB & 7)) << 4) + ((l4 & 1) << 3);
                f16x4 b = *(const f16x4*)(BsB[buf] + boff);
                acc[t] = __builtin_amdgcn_mfma_f32_16x16x16f16(a, b, acc[t], 0, 0, 0);
            }
        }
    };

    // prologue: stage phases 0 and 1 (12 DMAs in flight per wave)
    stageA(0, 0); stageB(0, 0);
    stageA(1, 1); stageB(1, 1);
    // steady state: compute(ph) from buf[ph&1]; stage(ph+2) into the freed buffer
    for (int ph = 0; ph <= 20; ++ph) {
        asm volatile("s_waitcnt vmcnt(6)" ::: "memory");   // buf[ph&1]'s 6 DMAs done
        __builtin_amdgcn_sched_barrier(0);
        __builtin_amdgcn_s_barrier();                      // all waves agree
        compute(ph & 1);
        asm volatile("s_waitcnt lgkmcnt(0)" ::: "memory"); // reads retired before overwrite
        __builtin_amdgcn_s_barrier();
        int nxt = ph + 2;
        if (nxt < 22)       { stageA(ph & 1, nxt); stageB(ph & 1, nxt); }
        else if (nxt == 22) { stageTailA(ph & 1);  stageB(ph & 1, 22);  }
    }
    // phases 21, 22: single drain
    asm volatile("s_waitcnt vmcnt(0) lgkmcnt(0)" ::: "memory");
    __builtin_amdgcn_sched_barrier(0);
    __builtin_amdgcn_s_barrier();
    compute(1);                            // phase 21 (buf1)
    compute(0);                            // phase 22 (buf0, tail)

    // epilogue: h1 write + fused attention coefficients (reduce over 8 channels)
    const int wrow0 = brow0 + wave * 16;
    #pragma unroll
    for (int t = 0; t < 4; ++t) {
        const int head = t * 2 + (l16 >> 3);
        const int ch   = l16 & 7;
        const float asc = att_src1[head * 8 + ch];
        const float adc = att_dst1[head * 8 + ch];
        #pragma unroll
        for (int j = 0; j < 4; ++j) {
            int r = wrow0 + l4 * 4 + j;    // C: col = lane&15, row = (lane>>4)*4 + reg
            float ps = acc[t][j] * asc, pd = acc[t][j] * adc;
            ps += __shfl_xor(ps, 1); ps += __shfl_xor(ps, 2); ps += __shfl_xor(ps, 4);
            pd += __shfl_xor(pd, 1); pd += __shfl_xor(pd, 2); pd += __shfl_xor(pd, 4);
            if (r < N_NODES) {
                h1[(size_t)r * 64 + t * 16 + l16] = (_Float16)acc[t][j];
                if (ch == 0) {
                    a_s1[r * 8 + head] = ps;
                    a_d1[r * 8 + head] = pd;
                }
            }
        }
    }
}

// ---------------- layer-1 aggregate (defer-max, 4-deep gather batching) ----------------
__global__ __launch_bounds__(256) void k_agg1(
    const int* __restrict__ offsets, const int* __restrict__ counts,
    const int* __restrict__ sorted_src,
    const float* __restrict__ a_s1, const float* __restrict__ a_d1,
    const _Float16* __restrict__ h1, const float* __restrict__ b1,
    const float* __restrict__ w2, const float* __restrict__ att_src2,
    const float* __restrict__ att_dst2,
    _Float16* __restrict__ g, float* __restrict__ a_s2, float* __restrict__ a_d2) {
    const int lane = threadIdx.x & 63;
    const int wave = threadIdx.x >> 6;
    const int h    = lane & 7;
    const int es   = lane >> 3;
    const int n    = blockIdx.x * 4 + wave;     // 25000*4 = 100000 exact
    const int start = offsets[n];
    const int cnt   = counts[n];
    const float adn = a_d1[n * 8 + h];
    float et = a_s1[n * 8 + h] + adn;
    const float e_self = et > 0.f ? et : 0.2f * et;

    float m = e_self, denom = 0.f;
    float acc[8] = {0.f,0.f,0.f,0.f,0.f,0.f,0.f,0.f};
    if (es == 0) {                 // self-loop: exp(e_self - m) = 1
        denom = 1.f;
        f16x8 hv0 = *(const f16x8*)(h1 + (size_t)n * 64 + h * 8);
        #pragma unroll
        for (int c = 0; c < 8; ++c) acc[c] = (float)hv0[c];
    }
    for (int i = es; i < cnt; i += 32) {
        const int i1 = i + 8, i2 = i + 16, i3 = i + 24;
        const bool b1v = i1 < cnt, b2v = i2 < cnt, b3v = i3 < cnt;
        int s0 = sorted_src[start + i];
        int s1 = sorted_src[start + (b1v ? i1 : i)];
        int s2 = sorted_src[start + (b2v ? i2 : i)];
        int s3 = sorted_src[start + (b3v ? i3 : i)];
        float a0 = a_s1[s0 * 8 + h];
        float a1 = a_s1[s1 * 8 + h];
        float a2 = a_s1[s2 * 8 + h];
        float a3 = a_s1[s3 * 8 + h];
        f16x8 v0 = *(const f16x8*)(h1 + (size_t)s0 * 64 + h * 8);
        f16x8 v1 = *(const f16x8*)(h1 + (size_t)s1 * 64 + h * 8);
        f16x8 v2 = *(const f16x8*)(h1 + (size_t)s2 * 64 + h * 8);
        f16x8 v3 = *(const f16x8*)(h1 + (size_t)s3 * 64 + h * 8);
        {
            float e = a0 + adn; e = e > 0.f ? e : 0.2f * e;
            if (e > m + 8.f) { float sc = __expf(m - e); denom *= sc;
                #pragma unroll
                for (int c = 0; c < 8; ++c) acc[c] *= sc; m = e; }
            float p = __expf(e - m); denom += p;
            #pragma unroll
            for (int c = 0; c < 8; ++c) acc[c] += p * (float)v0[c];
        }
        if (b1v) {
            float e = a1 + adn; e = e > 0.f ? e : 0.2f * e;
            if (e > m + 8.f) { float sc = __expf(m - e); denom *= sc;
                #pragma unroll
                for (int c = 0; c < 8; ++c) acc[c] *= sc; m = e; }
            float p = __expf(e - m); denom += p;
            #pragma unroll
            for (int c = 0; c < 8; ++c) acc[c] += p * (float)v1[c];
        }
        if (b2v) {
            float e = a2 + adn; e = e > 0.f ? e : 0.2f * e;
            if (e > m + 8.f) { float sc = __expf(m - e); denom *= sc;
                #pragma unroll
                for (int c = 0; c < 8; ++c) acc[c] *= sc; m = e; }
            float p = __expf(e - m); denom += p;
            #pragma unroll
            for (int c = 0; c < 8; ++c) acc[c] += p * (float)v2[c];
        }
        if (b3v) {
            float e = a3 + adn; e = e > 0.f ? e : 0.2f * e;
            if (e > m + 8.f) { float sc = __expf(m - e); denom *= sc;
                #pragma unroll
                for (int c = 0; c < 8; ++c) acc[c] *= sc; m = e; }
            float p = __expf(e - m); denom += p;
            #pragma unroll
            for (int c = 0; c < 8; ++c) acc[c] += p * (float)v3[c];
        }
    }
    // combine 8 edge-slots per head (xor 8,16,32); m may differ after rescales
    #pragma unroll
    for (int d = 8; d < 64; d <<= 1) {
        float mo = __shfl_xor(m, d);
        float dn = __shfl_xor(denom, d);
        float mn = fmaxf(m, mo);
        float sa = __expf(m - mn), sb = __expf(mo - mn);
        denom = denom * sa + dn * sb;
        #pragma unroll
        for (int c = 0; c < 8; ++c) {
            float ao = __shfl_xor(acc[c], d);
            acc[c] = acc[c] * sa + ao * sb;
        }
        m = mn;
    }
    float inv = 1.f / (denom + 1e-16f);
    float hc[8];
    #pragma unroll
    for (int c = 0; c < 8; ++c) {
        float v = acc[c] * inv;
        v += __shfl_xor(v, 1);
        v += __shfl_xor(v, 2);
        v += __shfl_xor(v, 4);                  // mean over heads
        float o = 0.125f * v + b1[c];
        hc[c] = o > 0.f ? o : expm1f(o);        // ELU
    }
    if (lane == 0) {
        float s2 = 0.f, d2 = 0.f;
        f16x8 gr;
        #pragma unroll
        for (int j = 0; j < 7; ++j) {
            float t = 0.f;
            #pragma unroll
            for (int c = 0; c < 8; ++c) t += hc[c] * w2[c * 7 + j];
            gr[j] = (_Float16)t;
            s2 += t * att_src2[j];
            d2 += t * att_dst2[j];
        }
        gr[7] = (_Float16)0.f;
        *(f16x8*)(g + (size_t)n * 8) = gr;
        a_s2[n] = s2;
        a_d2[n] = d2;
    }
}

// ---------------- layer-2 aggregate (defer-max, 4-deep batching) + log_softmax ----------------
__global__ __launch_bounds__(256) void k_agg2(
    const int* __restrict__ offsets, const int* __restrict__ counts,
    const int* __restrict__ sorted_src,
    const float* __restrict__ a_s2, const float* __restrict__ a_d2,
    const _Float16* __restrict__ g, const float* __restrict__ b2,
    float* __restrict__ outp) {
    const int tid  = threadIdx.x;
    const int lane = tid & 63;
    const int wave = tid >> 6;
    const int grp  = lane >> 3;
    const int s    = lane & 7;
    const int n    = blockIdx.x * 32 + wave * 8 + grp;
    const int start = offsets[n];
    const int cnt   = counts[n];
    const float adn = a_d2[n];
    float et = a_s2[n] + adn;
    const float e_self = et > 0.f ? et : 0.2f * et;

    float m = e_self, denom = 0.f;
    float acc[8] = {0.f,0.f,0.f,0.f,0.f,0.f,0.f,0.f};
    if (s == 0) {
        denom = 1.f;
        f16x8 gv0 = *(const f16x8*)(g + (size_t)n * 8);
        #pragma unroll
        for (int c = 0; c < 8; ++c) acc[c] = (float)gv0[c];
    }
    for (int i = s; i < cnt; i += 32) {
        const int i1 = i + 8, i2 = i + 16, i3 = i + 24;
        const bool b1v = i1 < cnt, b2v = i2 < cnt, b3v = i3 < cnt;
        int s0 = sorted_src[start + i];
        int s1 = sorted_src[start + (b1v ? i1 : i)];
        int s2 = sorted_src[start + (b2v ? i2 : i)];
        int s3 = sorted_src[start + (b3v ? i3 : i)];
        float a0 = a_s2[s0], a1 = a_s2[s1], a2 = a_s2[s2], a3 = a_s2[s3];
        f16x8 v0 = *(const f16x8*)(g + (size_t)s0 * 8);
        f16x8 v1 = *(const f16x8*)(g + (size_t)s1 * 8);
        f16x8 v2 = *(const f16x8*)(g + (size_t)s2 * 8);
        f16x8 v3 = *(const f16x8*)(g + (size_t)s3 * 8);
        {
            float e = a0 + adn; e = e > 0.f ? e : 0.2f * e;
            if (e > m + 8.f) { float sc = __expf(m - e); denom *= sc;
                #pragma unroll
                for (int c = 0; c < 8; ++c) acc[c] *= sc; m = e; }
            float p = __expf(e - m); denom += p;
            #pragma unroll
            for (int c = 0; c < 8; ++c) acc[c] += p * (float)v0[c];
        }
        if (b1v) {
            float e = a1 + adn; e = e > 0.f ? e : 0.2f * e;
            if (e > m + 8.f) { float sc = __expf(m - e); denom *= sc;
                #pragma unroll
                for (int c = 0; c < 8; ++c) acc[c] *= sc; m = e; }
            float p = __expf(e - m); denom += p;
            #pragma unroll
            for (int c = 0; c < 8; ++c) acc[c] += p * (float)v1[c];
        }
        if (b2v) {
            float e = a2 + adn; e = e > 0.f ? e : 0.2f * e;
            if (e > m + 8.f) { float sc = __expf(m - e); denom *= sc;
                #pragma unroll
                for (int c = 0; c < 8; ++c) acc[c] *= sc; m = e; }
            float p = __expf(e - m); denom += p;
            #pragma unroll
            for (int c = 0; c < 8; ++c) acc[c] += p * (float)v2[c];
        }
        if (b3v) {
            float e = a3 + adn; e = e > 0.f ? e : 0.2f * e;
            if (e > m + 8.f) { float sc = __expf(m - e); denom *= sc;
                #pragma unroll
                for (int c = 0; c < 8; ++c) acc[c] *= sc; m = e; }
            float p = __expf(e - m); denom += p;
            #pragma unroll
            for (int c = 0; c < 8; ++c) acc[c] += p * (float)v3[c];
        }
    }
    #pragma unroll
    for (int d = 1; d < 8; d <<= 1) {
        float mo = __shfl_xor(m, d, 8);
        float dn = __shfl_xor(denom, d, 8);
        float mn = fmaxf(m, mo);
        float sa = __expf(m - mn), sb = __expf(mo - mn);
        denom = denom * sa + dn * sb;
        #pragma unroll
        for (int c = 0; c < 8; ++c) {
            float ao = __shfl_xor(acc[c], d, 8);
            acc[c] = acc[c] * sa + ao * sb;
        }
        m = mn;
    }
    float inv = 1.f / (denom + 1e-16f);
    float o[7]; float mx = -1e30f;
    #pragma unroll
    for (int c = 0; c < 7; ++c) { o[c] = acc[c] * inv + b2[c]; mx = fmaxf(mx, o[c]); }
    float se = 0.f;
    #pragma unroll
    for (int c = 0; c < 7; ++c) se += __expf(o[c] - mx);
    float ls = mx + logf(se);
    if (s < 7) outp[n * 7 + s] = o[s] - ls;
}

extern "C" void kernel_launch(void* const* d_in, const int* in_sizes, int n_in,
                              void* d_out, int out_size, void* d_ws, size_t ws_size,
                              hipStream_t stream) {
    const float* x        = (const float*)d_in[0];
    const int*   ei       = (const int*)d_in[1];
    const float* W1       = (const float*)d_in[2];
    const float* att_src1 = (const float*)d_in[3];
    const float* att_dst1 = (const float*)d_in[4];
    const float* b1       = (const float*)d_in[5];
    const float* W2       = (const float*)d_in[6];
    const float* att_src2 = (const float*)d_in[7];
    const float* att_dst2 = (const float*)d_in[8];
    const float* b2       = (const float*)d_in[9];
    const int* src = ei;
    const int* dst = ei + E_EDGES;

    char* ws = (char*)d_ws;
    size_t off = 0;
    auto alloc = [&](size_t bytes) -> char* {
        char* p = ws + off;
        off = (off + bytes + 255) & ~(size_t)255;
        return p;
    };
    _Float16* h1         = (_Float16*)alloc((size_t)N_NODES * 64 * 2);
    float*    a_s1       = (float*)   alloc((size_t)N_NODES * 8 * 4);
    float*    a_d1       = (float*)   alloc((size_t)N_NODES * 8 * 4);
    _Float16* w1t        = (_Float16*)alloc((size_t)64 * K_PAD * 2);
    int*      counts     = (int*)     alloc((size_t)N_NODES * 4);
    int*      offsets    = (int*)     alloc((size_t)N_NODES * 4);
    int*      cursor     = (int*)     alloc((size_t)N_NODES * 4);
    int*      csum       = (int*)     alloc((size_t)NCH * 4);
    int*      sorted_src = (int*)     alloc((size_t)(E_EDGES + 32) * 4);
    _Float16* gbuf       = (_Float16*)alloc((size_t)N_NODES * 8 * 2);
    float*    a_s2       = (float*)   alloc((size_t)N_NODES * 4);
    float*    a_d2       = (float*)   alloc((size_t)N_NODES * 4);
    float*    outp       = (float*)d_out;

    hipLaunchKernelGGL(k_init,      dim3(391),   dim3(256), 0, stream, W1, w1t, counts);
    hipLaunchKernelGGL(k_hist,      dim3(3125),  dim3(256), 0, stream, dst, counts);
    hipLaunchKernelGGL(k_scan_a,    dim3(NCH),   dim3(256), 0, stream, counts, csum);
    hipLaunchKernelGGL(k_scan_b,    dim3(1),     dim3(128), 0, stream, csum);
    hipLaunchKernelGGL(k_scan_c,    dim3(NCH),   dim3(256), 0, stream, counts, csum, offsets, cursor);
    hipLaunchKernelGGL(k_gemm_scat, dim3(3126),  dim3(256), 0, stream,
                       x, w1t, att_src1, att_dst1, h1, a_s1, a_d1,
                       src, dst, cursor, sorted_src);
    hipLaunchKernelGGL(k_agg1,      dim3(25000), dim3(256), 0, stream, offsets, counts, sorted_src,
                       a_s1, a_d1, h1, b1, W2, att_src2, att_dst2, gbuf, a_s2, a_d2);
    hipLaunchKernelGGL(k_agg2,      dim3(3125),  dim3(256), 0, stream, offsets, counts, sorted_src,
                       a_s2, a_d2, gbuf, b2, outp);
}